// Round 1
// baseline (2007.432 us; speedup 1.0000x reference)
//
#include <hip/hip_runtime.h>
#include <stdint.h>

// Problem constants
#define Bz 32
#define Tz 64
#define Nz 1000
#define Cz 8
#define HGz 16
#define HLz 256
#define OUTz 24
#define Ez 16000
#define Kz 16000   // N*HG
#define Mz 2048    // B*T
#define G4z 1024   // 4*HL

using half8  = __attribute__((ext_vector_type(8))) _Float16;
using half2v = __attribute__((ext_vector_type(2))) _Float16;
using floatx4 = __attribute__((ext_vector_type(4))) float;

// Workspace layout (bytes, 256-aligned)
static const size_t OFF_SEQ   = 0;          // seq fp16 [2048][16000]  65,536,000
static const size_t OFF_WIH   = 65536000;   // W_ih fp16 [1024][16000] 32,768,000
static const size_t OFF_PRE   = 98304000;   // pre fp32 [2048][1024]    8,388,608
static const size_t OFF_XW0   = 106692608;  // xw0 fp32 [64][1000][16]  4,096,000
static const size_t OFF_AGG   = 110788608;  // agg fp32 [64][1000][16]  4,096,000
static const size_t OFF_DEG   = 114884608;  // deg fp32 [1000]
static const size_t OFF_IDEG  = 114888704;  // inv_deg fp32 [1000]
static const size_t OFF_NORM  = 114892800;  // norm fp32 [16000]
static const size_t OFF_HBUF  = 114957056;  // h fp32 [2][32][256]     65,536
static const size_t OFF_HLAST = 115022592;  // h_last fp32 [32][256]   32,768
static const size_t OFF_CTR   = 115055360;  // barrier counters [64]
static const size_t WS_NEED   = 115055616;

__device__ __forceinline__ void gl_lds16(const void* g, void* l) {
  __builtin_amdgcn_global_load_lds(
      (__attribute__((address_space(1))) void*)(void*)g,
      (__attribute__((address_space(3))) void*)l, 16, 0, 0);
}

__device__ __forceinline__ float sigm(float x) { return 1.0f / (1.0f + __expf(-x)); }
__device__ __forceinline__ float tanhh(float x) { return 1.0f - 2.0f / (__expf(2.0f * x) + 1.0f); }

// ---------------- GCN prep ----------------
__global__ void k_deg_init(float* deg) {
  int i = blockIdx.x * 256 + threadIdx.x;
  if (i < Nz) deg[i] = 1.0f;
}

__global__ void k_deg_scatter(const int* __restrict__ ei, const float* __restrict__ ew,
                              float* deg) {
  int e = blockIdx.x * 256 + threadIdx.x;
  if (e < Ez) atomicAdd(&deg[ei[Ez + e]], ew[e]);
}

__global__ void k_norm(const int* __restrict__ ei, const float* __restrict__ ew,
                       const float* __restrict__ deg, float* __restrict__ norm,
                       float* __restrict__ ideg) {
  int e = blockIdx.x * 256 + threadIdx.x;
  if (e < Ez) {
    float dr = deg[ei[e]], dc = deg[ei[Ez + e]];
    norm[e] = ew[e] * (1.0f / sqrtf(dr)) * (1.0f / sqrtf(dc));
  }
  if (e < Nz) ideg[e] = 1.0f / deg[e];
}

// fp32 -> fp16 bulk convert (8 elems/thread)
__global__ void k_f32tof16(const float* __restrict__ src, _Float16* __restrict__ dst,
                           size_t n8) {
  size_t i = (size_t)blockIdx.x * 256 + threadIdx.x;
  if (i >= n8) return;
  float4 a = ((const float4*)src)[i * 2];
  float4 b = ((const float4*)src)[i * 2 + 1];
  half8 h;
  h[0] = (_Float16)a.x; h[1] = (_Float16)a.y; h[2] = (_Float16)a.z; h[3] = (_Float16)a.w;
  h[4] = (_Float16)b.x; h[5] = (_Float16)b.y; h[6] = (_Float16)b.z; h[7] = (_Float16)b.w;
  ((half8*)dst)[i] = h;
}

// xw0[t,n,h] = x[0,t,n,:] @ W_gcn  (batch 0, pre-aggregation)
__global__ void k_xw0(const float* __restrict__ x, const float* __restrict__ Wg,
                      float* __restrict__ xw0) {
  __shared__ float wgs[Cz * HGz];
  if (threadIdx.x < Cz * HGz) wgs[threadIdx.x] = Wg[threadIdx.x];
  __syncthreads();
  int idx = blockIdx.x * 256 + threadIdx.x;
  if (idx >= Tz * Nz) return;
  const float* xp = x + (size_t)idx * Cz;
  float4 v0 = *(const float4*)xp, v1 = *(const float4*)(xp + 4);
  float xv[8] = {v0.x, v0.y, v0.z, v0.w, v1.x, v1.y, v1.z, v1.w};
  float* op = xw0 + (size_t)idx * HGz;
#pragma unroll
  for (int h = 0; h < HGz; h += 4) {
    float4 o;
    float* po = (float*)&o;
#pragma unroll
    for (int j = 0; j < 4; ++j) {
      float s = 0.f;
#pragma unroll
      for (int c = 0; c < Cz; ++c) s += xv[c] * wgs[c * HGz + h + j];
      po[j] = s;
    }
    *(float4*)&op[h] = o;
  }
}

// agg[t, col[e], :] += norm[e] * xw0[t, row[e], :]
__global__ void k_agg(const int* __restrict__ ei, const float* __restrict__ norm,
                      const float* __restrict__ xw0, float* __restrict__ agg) {
  int idx = blockIdx.x * 256 + threadIdx.x;
  if (idx >= Tz * Ez) return;
  int e = idx % Ez, t = idx / Ez;
  int src = ei[e], dst = ei[Ez + e];
  float nv = norm[e];
  const float* sp = xw0 + ((size_t)t * Nz + src) * HGz;
  float* dp = agg + ((size_t)t * Nz + dst) * HGz;
#pragma unroll
  for (int h = 0; h < HGz; ++h) atomicAdd(&dp[h], nv * sp[h]);
}

// seq[b*T+t, n*16+h] = fp16( GCN output )
__global__ void k_seq(const float* __restrict__ x, const float* __restrict__ Wg,
                      const float* __restrict__ bg, const float* __restrict__ ideg,
                      const float* __restrict__ agg, _Float16* __restrict__ seq) {
  __shared__ float wgs[Cz * HGz];
  __shared__ float bgs[HGz];
  if (threadIdx.x < Cz * HGz) wgs[threadIdx.x] = Wg[threadIdx.x];
  if (threadIdx.x < HGz) bgs[threadIdx.x] = bg[threadIdx.x];
  __syncthreads();
  int idx = blockIdx.x * 256 + threadIdx.x;
  if (idx >= Mz * Nz) return;
  int n = idx % Nz;
  int bt = idx / Nz;
  const float* xp = x + (size_t)idx * Cz;
  float4 v0 = *(const float4*)xp, v1 = *(const float4*)(xp + 4);
  float xv[8] = {v0.x, v0.y, v0.z, v0.w, v1.x, v1.y, v1.z, v1.w};
  float s[HGz];
#pragma unroll
  for (int h = 0; h < HGz; ++h) {
    float a = 0.f;
#pragma unroll
    for (int c = 0; c < Cz; ++c) a += xv[c] * wgs[c * HGz + h];
    s[h] = a;
  }
  if (bt < Tz) {  // batch 0: scale by 1/deg and add neighbor aggregation
    float id = ideg[n];
    const float* ag = agg + ((size_t)bt * Nz + n) * HGz;
#pragma unroll
    for (int h = 0; h < HGz; ++h) s[h] = s[h] * id + ag[h];
  }
#pragma unroll
  for (int h = 0; h < HGz; ++h) s[h] += bgs[h];
  half8 h0, h1;
#pragma unroll
  for (int j = 0; j < 8; ++j) { h0[j] = (_Float16)s[j]; h1[j] = (_Float16)s[8 + j]; }
  half8* op = (half8*)(seq + (size_t)bt * Kz + n * HGz);
  op[0] = h0;
  op[1] = h1;
}

// ---------------- big GEMM: pre[2048,1024] += seq @ W_ih^T (split-K=4) ----------------
__global__ void __launch_bounds__(256) k_gemm(const _Float16* __restrict__ A,
                                              const _Float16* __restrict__ Bm,
                                              float* __restrict__ Cp) {
  __shared__ _Float16 As[128 * 32];
  __shared__ _Float16 Bs[128 * 32];
  const int tid = threadIdx.x;
  const int lane = tid & 63;
  const int wave = tid >> 6;
  const int wm = wave & 1, wn = wave >> 1;
  const int quad = lane >> 4, l15 = lane & 15;
  const size_t tm = (size_t)blockIdx.x * 128;
  const size_t tn = (size_t)blockIdx.y * 128;
  const int k0 = blockIdx.z * 4000;
  const int srow = tid >> 2;
  const int skk = (tid & 3) * 8;
  const _Float16* gA0 = A + (tm + srow) * (size_t)Kz + k0 + skk;
  const _Float16* gA1 = gA0 + 64 * (size_t)Kz;
  const _Float16* gB0 = Bm + (tn + srow) * (size_t)Kz + k0 + skk;
  const _Float16* gB1 = gB0 + 64 * (size_t)Kz;
  _Float16* lA0 = &As[tid * 8];
  _Float16* lA1 = &As[2048 + tid * 8];
  _Float16* lB0 = &Bs[tid * 8];
  _Float16* lB1 = &Bs[2048 + tid * 8];
  floatx4 acc[4][4] = {};
  for (int kt = 0; kt < 125; ++kt) {
    __syncthreads();
    gl_lds16(gA0, lA0);
    gl_lds16(gA1, lA1);
    gl_lds16(gB0, lB0);
    gl_lds16(gB1, lB1);
    gA0 += 32; gA1 += 32; gB0 += 32; gB1 += 32;
    __syncthreads();
    half8 af[4], bf[4];
#pragma unroll
    for (int i = 0; i < 4; ++i)
      af[i] = *(const half8*)&As[(wm * 64 + i * 16 + l15) * 32 + quad * 8];
#pragma unroll
    for (int i = 0; i < 4; ++i)
      bf[i] = *(const half8*)&Bs[(wn * 64 + i * 16 + l15) * 32 + quad * 8];
#pragma unroll
    for (int mi = 0; mi < 4; ++mi)
#pragma unroll
      for (int ni = 0; ni < 4; ++ni)
        acc[mi][ni] = __builtin_amdgcn_mfma_f32_16x16x32_f16(af[mi], bf[ni], acc[mi][ni], 0, 0, 0);
  }
#pragma unroll
  for (int mi = 0; mi < 4; ++mi)
#pragma unroll
    for (int ni = 0; ni < 4; ++ni) {
      size_t r0 = tm + wm * 64 + mi * 16 + quad * 4;
      size_t cc = tn + wn * 64 + ni * 16 + l15;
#pragma unroll
      for (int q = 0; q < 4; ++q) atomicAdd(&Cp[(r0 + q) * G4z + cc], acc[mi][ni][q]);
    }
}

// ---------------- persistent LSTM: 16 WGs, slice HL by 16, spin barrier per step ----------------
__global__ void __launch_bounds__(128) k_lstm(const float* __restrict__ pre,
                                              const float* __restrict__ Whh,
                                              const float* __restrict__ bih,
                                              const float* __restrict__ bhh,
                                              float* __restrict__ hbuf,  // [2][32][256] fp32
                                              int* __restrict__ ctr,     // [64]
                                              float* __restrict__ hlast) // [32][256]
{
  __shared__ _Float16 Wt[64 * 264];   // 64 rows (4 gates x 16 hl), padded stride 264
  __shared__ _Float16 hs[32 * 264];   // h as fp16, padded
  __shared__ float bias_s[64];
  const int tid = threadIdx.x;
  const int w = blockIdx.x;  // hl slice [w*16, w*16+16)
  // stage W_hh slice into LDS as fp16 (row jr = gate*16 + r -> global j = gate*256 + w*16 + r)
  {
    int jr = tid >> 1, hh = tid & 1;
    int jglob = (jr >> 4) * HLz + w * 16 + (jr & 15);
    const float* srcp = Whh + (size_t)jglob * HLz + hh * 128;
    _Float16* dstp = &Wt[jr * 264 + hh * 128];
    for (int k = 0; k < 128; k += 4) {
      float4 v = *(const float4*)&srcp[k];
      dstp[k] = (_Float16)v.x; dstp[k + 1] = (_Float16)v.y;
      dstp[k + 2] = (_Float16)v.z; dstp[k + 3] = (_Float16)v.w;
    }
    if (tid < 64) {
      int jg = (tid >> 4) * HLz + w * 16 + (tid & 15);
      bias_s[tid] = bih[jg] + bhh[jg];
    }
  }
  const int lane = tid & 63, wave = tid >> 6;
  const int quad = lane >> 4, l15 = lane & 15;
  float cst[4] = {0.f, 0.f, 0.f, 0.f};
  __syncthreads();

  for (int t = 0; t < Tz; ++t) {
    // load h(t) from global (agent-scope atomics: cross-XCD coherent) into LDS fp16
    const unsigned long long* hb =
        (const unsigned long long*)(hbuf + (size_t)(t & 1) * Bz * HLz);
    for (int i = tid; i < Bz * HLz / 2; i += 128) {
      unsigned long long u =
          __hip_atomic_load(hb + i, __ATOMIC_RELAXED, __HIP_MEMORY_SCOPE_AGENT);
      union { unsigned long long u64; float f[2]; } cv;
      cv.u64 = u;
      int flat = i * 2;
      int bb = flat >> 8, kk = flat & 255;
      half2v hv;
      hv.x = (_Float16)cv.f[0];
      hv.y = (_Float16)cv.f[1];
      *(half2v*)&hs[bb * 264 + kk] = hv;
    }
    __syncthreads();
    // gates slice: [32 batches] x [64 j-rows]  = h[32,256] @ Wt^T
    floatx4 acc[4] = {};
#pragma unroll
    for (int ks = 0; ks < 8; ++ks) {
      half8 a = *(const half8*)&hs[(wave * 16 + l15) * 264 + ks * 32 + quad * 8];
#pragma unroll
      for (int ni = 0; ni < 4; ++ni) {
        half8 b = *(const half8*)&Wt[(ni * 16 + l15) * 264 + ks * 32 + quad * 8];
        acc[ni] = __builtin_amdgcn_mfma_f32_16x16x32_f16(a, b, acc[ni], 0, 0, 0);
      }
    }
    float* hb_next = hbuf + (size_t)((t + 1) & 1) * Bz * HLz;
#pragma unroll
    for (int q = 0; q < 4; ++q) {
      int batch = wave * 16 + quad * 4 + q;
      const float* prow = pre + ((size_t)batch * Tz + t) * G4z;
      int jc = w * 16 + l15;
      float gi = acc[0][q] + prow[jc] + bias_s[l15];
      float gf = acc[1][q] + prow[256 + jc] + bias_s[16 + l15];
      float gg = acc[2][q] + prow[512 + jc] + bias_s[32 + l15];
      float go = acc[3][q] + prow[768 + jc] + bias_s[48 + l15];
      float iv = sigm(gi), fv = sigm(gf), gv = tanhh(gg), ov = sigm(go);
      float cn = fv * cst[q] + iv * gv;
      cst[q] = cn;
      float hn = ov * tanhh(cn);
      if (t < Tz - 1) {
        __hip_atomic_store(&hb_next[batch * HLz + jc], hn, __ATOMIC_RELAXED,
                           __HIP_MEMORY_SCOPE_AGENT);
      } else {
        hlast[batch * HLz + jc] = hn;
      }
    }
    if (t < Tz - 1) {
      __syncthreads();
      if (tid == 0) {
        __threadfence();
        __hip_atomic_fetch_add(&ctr[t], 1, __ATOMIC_RELEASE, __HIP_MEMORY_SCOPE_AGENT);
        while (__hip_atomic_load(&ctr[t], __ATOMIC_ACQUIRE, __HIP_MEMORY_SCOPE_AGENT) < 16)
          __builtin_amdgcn_s_sleep(2);
      }
      __syncthreads();
    }
  }
}

// out[b,o] = h_last[b,:] @ W_proj[o,:] + b_proj[o]
__global__ void k_proj(const float* __restrict__ hlast, const float* __restrict__ Wp,
                       const float* __restrict__ bp, float* __restrict__ out) {
  int idx = blockIdx.x * 256 + threadIdx.x;
  if (idx >= Bz * OUTz) return;
  int b = idx / OUTz, o = idx % OUTz;
  const float* h = hlast + (size_t)b * HLz;
  const float* wr = Wp + (size_t)o * HLz;
  float s = 0.f;
  for (int k = 0; k < HLz; k += 4) {
    float4 hv = *(const float4*)&h[k];
    float4 wv = *(const float4*)&wr[k];
    s += hv.x * wv.x + hv.y * wv.y + hv.z * wv.z + hv.w * wv.w;
  }
  out[idx] = s + bp[o];
}

extern "C" void kernel_launch(void* const* d_in, const int* in_sizes, int n_in,
                              void* d_out, int out_size, void* d_ws, size_t ws_size,
                              hipStream_t stream) {
  const float* x   = (const float*)d_in[0];
  const int*   ei  = (const int*)d_in[1];
  const float* ew  = (const float*)d_in[2];
  const float* Wg  = (const float*)d_in[3];
  const float* bg  = (const float*)d_in[4];
  const float* Wih = (const float*)d_in[5];
  const float* Whh = (const float*)d_in[6];
  const float* bih = (const float*)d_in[7];
  const float* bhh = (const float*)d_in[8];
  const float* Wp  = (const float*)d_in[9];
  const float* bp  = (const float*)d_in[10];
  float* out = (float*)d_out;
  char* ws = (char*)d_ws;
  if (ws_size < WS_NEED) return;

  _Float16* seq16 = (_Float16*)(ws + OFF_SEQ);
  _Float16* wih16 = (_Float16*)(ws + OFF_WIH);
  float* pre   = (float*)(ws + OFF_PRE);
  float* xw0   = (float*)(ws + OFF_XW0);
  float* agg   = (float*)(ws + OFF_AGG);
  float* deg   = (float*)(ws + OFF_DEG);
  float* ideg  = (float*)(ws + OFF_IDEG);
  float* norm  = (float*)(ws + OFF_NORM);
  float* hbuf  = (float*)(ws + OFF_HBUF);
  float* hlast = (float*)(ws + OFF_HLAST);
  int*   ctr   = (int*)(ws + OFF_CTR);

  hipMemsetAsync(pre, 0, (size_t)Mz * G4z * 4, stream);
  hipMemsetAsync(agg, 0, (size_t)Tz * Nz * HGz * 4, stream);
  hipMemsetAsync(hbuf, 0, (OFF_CTR + 256) - OFF_HBUF, stream);

  k_deg_init<<<4, 256, 0, stream>>>(deg);
  k_deg_scatter<<<63, 256, 0, stream>>>(ei, ew, deg);
  k_norm<<<63, 256, 0, stream>>>(ei, ew, deg, norm, ideg);
  k_f32tof16<<<8000, 256, 0, stream>>>(Wih, wih16, (size_t)G4z * Kz / 8);
  k_xw0<<<250, 256, 0, stream>>>(x, Wg, xw0);
  k_agg<<<4000, 256, 0, stream>>>(ei, norm, xw0, agg);
  k_seq<<<8000, 256, 0, stream>>>(x, Wg, bg, ideg, agg, seq16);
  k_gemm<<<dim3(16, 8, 4), 256, 0, stream>>>(seq16, wih16, pre);
  k_lstm<<<16, 128, 0, stream>>>(pre, Whh, bih, bhh, hbuf, ctr, hlast);
  k_proj<<<3, 256, 0, stream>>>(hlast, Wp, bp, out);
}

// Round 2
// 1410.905 us; speedup vs baseline: 1.4228x; 1.4228x over previous
//
#include <hip/hip_runtime.h>
#include <stdint.h>

// Problem constants
#define Bz 32
#define Tz 64
#define Nz 1000
#define Cz 8
#define HGz 16
#define HLz 256
#define OUTz 24
#define Ez 16000
#define Kz 16000   // N*HG
#define Mz 2048    // B*T
#define G4z 1024   // 4*HL

using half8  = __attribute__((ext_vector_type(8))) _Float16;
using half4  = __attribute__((ext_vector_type(4))) _Float16;
using half2v = __attribute__((ext_vector_type(2))) _Float16;
using floatx4 = __attribute__((ext_vector_type(4))) float;

// ---- Workspace layout (bytes). Smalls first (fixed), big buffers after. ----
static const size_t OFF_DEG   = 0;        // fp32 [1000]
static const size_t OFF_IDEG  = 4096;     // fp32 [1000]
static const size_t OFF_NORM  = 8192;     // fp32 [16000]
static const size_t OFF_CNT   = 73728;    // int  [1024]
static const size_t OFF_ROFF  = 77824;    // int  [1024]
static const size_t OFF_CUR   = 81920;    // int  [1024]
static const size_t OFF_CSRS  = 86016;    // int  [16000]
static const size_t OFF_CSRW  = 151552;   // fp32 [16000]
static const size_t OFF_HBUF  = 217088;   // fp32 [2][32][256]
static const size_t OFF_HLAST = 282624;   // fp32 [32][256]
static const size_t OFF_CTR   = 315392;   // int [64]
static const size_t OFF_SEQ   = 327680;   // fp16 [2048][16000]  65,536,000
static const size_t OFF_WIH   = 65863680; // fp16 [1024][16000]  32,768,000
static const size_t OFF_PRES  = 98631680; // fp32 [NS][2048][1024], 8,388,608 per split
static const size_t SPLIT_BYTES = 8388608;

__device__ __forceinline__ void gl_lds16(const void* g, void* l) {
  __builtin_amdgcn_global_load_lds(
      (__attribute__((address_space(1))) void*)(void*)g,
      (__attribute__((address_space(3))) void*)l, 16, 0, 0);
}

__device__ __forceinline__ float sigm(float x) { return 1.0f / (1.0f + __expf(-x)); }
__device__ __forceinline__ float tanhh(float x) { return 1.0f - 2.0f / (__expf(2.0f * x) + 1.0f); }

// ---------------- GCN prep ----------------
__global__ void k_deg_init(float* deg) {
  int i = blockIdx.x * 256 + threadIdx.x;
  if (i < Nz) deg[i] = 1.0f;
}

__global__ void k_deg_scatter(const int* __restrict__ ei, const float* __restrict__ ew,
                              float* deg) {
  int e = blockIdx.x * 256 + threadIdx.x;
  if (e < Ez) atomicAdd(&deg[ei[Ez + e]], ew[e]);
}

__global__ void k_norm(const int* __restrict__ ei, const float* __restrict__ ew,
                       const float* __restrict__ deg, float* __restrict__ norm,
                       float* __restrict__ ideg) {
  int e = blockIdx.x * 256 + threadIdx.x;
  if (e < Ez) {
    float dr = deg[ei[e]], dc = deg[ei[Ez + e]];
    norm[e] = ew[e] * (1.0f / sqrtf(dr)) * (1.0f / sqrtf(dc));
  }
  if (e < Nz) ideg[e] = 1.0f / deg[e];
}

// CSR build: count edges per destination
__global__ void k_csr_count(const int* __restrict__ ei, int* __restrict__ cnt) {
  int e = blockIdx.x * 256 + threadIdx.x;
  if (e < Ez) atomicAdd(&cnt[ei[Ez + e]], 1);
}

// exclusive scan over 1024 counts (single 1024-thread WG)
__global__ void k_scan(const int* __restrict__ cnt, int* __restrict__ roff,
                       int* __restrict__ cur) {
  __shared__ int s[1024];
  int tid = threadIdx.x;
  int v0 = (tid < 1024) ? cnt[tid] : 0;
  s[tid] = v0;
  __syncthreads();
  for (int off = 1; off < 1024; off <<= 1) {
    int v = (tid >= off) ? s[tid - off] : 0;
    __syncthreads();
    s[tid] += v;
    __syncthreads();
  }
  int excl = s[tid] - v0;
  roff[tid] = excl;
  cur[tid] = excl;
}

__global__ void k_csr_fill(const int* __restrict__ ei, const float* __restrict__ norm,
                           int* __restrict__ cur, int* __restrict__ csrs,
                           float* __restrict__ csrw) {
  int e = blockIdx.x * 256 + threadIdx.x;
  if (e >= Ez) return;
  int dst = ei[Ez + e];
  int p = atomicAdd(&cur[dst], 1);
  csrs[p] = ei[e];
  csrw[p] = norm[e];
}

// fp32 -> fp16 bulk convert (8 elems/thread)
__global__ void k_f32tof16(const float* __restrict__ src, _Float16* __restrict__ dst,
                           size_t n8) {
  size_t i = (size_t)blockIdx.x * 256 + threadIdx.x;
  if (i >= n8) return;
  float4 a = ((const float4*)src)[i * 2];
  float4 b = ((const float4*)src)[i * 2 + 1];
  half8 h;
  h[0] = (_Float16)a.x; h[1] = (_Float16)a.y; h[2] = (_Float16)a.z; h[3] = (_Float16)a.w;
  h[4] = (_Float16)b.x; h[5] = (_Float16)b.y; h[6] = (_Float16)b.z; h[7] = (_Float16)b.w;
  ((half8*)dst)[i] = h;
}

// seq[bt, n*16+h] = fp16( xw (*ideg for batch0) + b_gcn )
__global__ void k_seq(const float* __restrict__ x, const float* __restrict__ Wg,
                      const float* __restrict__ bg, const float* __restrict__ ideg,
                      _Float16* __restrict__ seq) {
  __shared__ float wgs[Cz * HGz];
  __shared__ float bgs[HGz];
  if (threadIdx.x < Cz * HGz) wgs[threadIdx.x] = Wg[threadIdx.x];
  if (threadIdx.x < HGz) bgs[threadIdx.x] = bg[threadIdx.x];
  __syncthreads();
  int idx = blockIdx.x * 256 + threadIdx.x;
  if (idx >= Mz * Nz) return;
  int n = idx % Nz;
  int bt = idx / Nz;
  const float* xp = x + (size_t)idx * Cz;
  float4 v0 = *(const float4*)xp, v1 = *(const float4*)(xp + 4);
  float xv[8] = {v0.x, v0.y, v0.z, v0.w, v1.x, v1.y, v1.z, v1.w};
  float s[HGz];
#pragma unroll
  for (int h = 0; h < HGz; ++h) {
    float a = 0.f;
#pragma unroll
    for (int c = 0; c < Cz; ++c) a += xv[c] * wgs[c * HGz + h];
    s[h] = a;
  }
  float id = (bt < Tz) ? ideg[n] : 1.0f;
#pragma unroll
  for (int h = 0; h < HGz; ++h) s[h] = s[h] * id + bgs[h];
  half8 h0, h1;
#pragma unroll
  for (int j = 0; j < 8; ++j) { h0[j] = (_Float16)s[j]; h1[j] = (_Float16)s[8 + j]; }
  half8* op = (half8*)(seq + (size_t)bt * Kz + n * HGz);
  op[0] = h0;
  op[1] = h1;
}

// Neighbor aggregation for batch 0, CSR gather, fused x@W_gcn, RMW into seq fp16.
// thread = (t, n, hq): hq covers h in [hq*4, hq*4+4)
__global__ void k_aggseq(const float* __restrict__ x, const float* __restrict__ Wg,
                         const int* __restrict__ roff, const int* __restrict__ cnt,
                         const int* __restrict__ csrs, const float* __restrict__ csrw,
                         _Float16* __restrict__ seq) {
  __shared__ float wgs[Cz * HGz];
  if (threadIdx.x < Cz * HGz) wgs[threadIdx.x] = Wg[threadIdx.x];
  __syncthreads();
  int g = blockIdx.x * 256 + threadIdx.x;
  if (g >= Tz * Nz * 4) return;
  int t = g / (Nz * 4);
  int r = g % (Nz * 4);
  int n = r >> 2;
  int hq = r & 3;
  int nc = cnt[n];
  if (nc == 0) return;
  float w0[Cz], w1[Cz], w2[Cz], w3[Cz];
#pragma unroll
  for (int c = 0; c < Cz; ++c) {
    w0[c] = wgs[c * HGz + hq * 4 + 0];
    w1[c] = wgs[c * HGz + hq * 4 + 1];
    w2[c] = wgs[c * HGz + hq * 4 + 2];
    w3[c] = wgs[c * HGz + hq * 4 + 3];
  }
  float s0 = 0.f, s1 = 0.f, s2 = 0.f, s3 = 0.f;
  int i0 = roff[n];
  for (int i = i0; i < i0 + nc; ++i) {
    int src = csrs[i];
    float wv = csrw[i];
    const float* xp = x + ((size_t)t * Nz + src) * Cz;
    float4 a = *(const float4*)xp;
    float4 b = *(const float4*)(xp + 4);
    float xv[8] = {a.x, a.y, a.z, a.w, b.x, b.y, b.z, b.w};
    float m0 = 0.f, m1 = 0.f, m2 = 0.f, m3 = 0.f;
#pragma unroll
    for (int c = 0; c < Cz; ++c) {
      m0 += xv[c] * w0[c];
      m1 += xv[c] * w1[c];
      m2 += xv[c] * w2[c];
      m3 += xv[c] * w3[c];
    }
    s0 += wv * m0; s1 += wv * m1; s2 += wv * m2; s3 += wv * m3;
  }
  // RMW seq row (batch 0 occupies bt = t)
  half4* p = (half4*)(seq + (size_t)t * Kz + n * HGz + hq * 4);
  half4 hv = *p;
  hv[0] = (_Float16)((float)hv[0] + s0);
  hv[1] = (_Float16)((float)hv[1] + s1);
  hv[2] = (_Float16)((float)hv[2] + s2);
  hv[3] = (_Float16)((float)hv[3] + s3);
  *p = hv;
}

// ---------------- big GEMM: preS[z][2048][1024] = seq @ W_ih^T (split-K, plain stores) ----------------
__global__ void __launch_bounds__(256) k_gemm(const _Float16* __restrict__ A,
                                              const _Float16* __restrict__ Bm,
                                              float* __restrict__ Cp,
                                              int kLen, int iters) {
  __shared__ _Float16 As[128 * 32];
  __shared__ _Float16 Bs[128 * 32];
  const int tid = threadIdx.x;
  const int lane = tid & 63;
  const int wave = tid >> 6;
  const int wm = wave & 1, wn = wave >> 1;
  const int quad = lane >> 4, l15 = lane & 15;
  const size_t tm = (size_t)blockIdx.x * 128;
  const size_t tn = (size_t)blockIdx.y * 128;
  const int k0 = blockIdx.z * kLen;
  float* Cz_ = Cp + (size_t)blockIdx.z * Mz * G4z;
  const int srow = tid >> 2;
  const int skk = (tid & 3) * 8;
  const _Float16* gA0 = A + (tm + srow) * (size_t)Kz + k0 + skk;
  const _Float16* gA1 = gA0 + 64 * (size_t)Kz;
  const _Float16* gB0 = Bm + (tn + srow) * (size_t)Kz + k0 + skk;
  const _Float16* gB1 = gB0 + 64 * (size_t)Kz;
  _Float16* lA0 = &As[tid * 8];
  _Float16* lA1 = &As[2048 + tid * 8];
  _Float16* lB0 = &Bs[tid * 8];
  _Float16* lB1 = &Bs[2048 + tid * 8];
  floatx4 acc[4][4] = {};
  for (int kt = 0; kt < iters; ++kt) {
    __syncthreads();
    gl_lds16(gA0, lA0);
    gl_lds16(gA1, lA1);
    gl_lds16(gB0, lB0);
    gl_lds16(gB1, lB1);
    gA0 += 32; gA1 += 32; gB0 += 32; gB1 += 32;
    __syncthreads();
    half8 af[4], bf[4];
#pragma unroll
    for (int i = 0; i < 4; ++i)
      af[i] = *(const half8*)&As[(wm * 64 + i * 16 + l15) * 32 + quad * 8];
#pragma unroll
    for (int i = 0; i < 4; ++i)
      bf[i] = *(const half8*)&Bs[(wn * 64 + i * 16 + l15) * 32 + quad * 8];
#pragma unroll
    for (int mi = 0; mi < 4; ++mi)
#pragma unroll
      for (int ni = 0; ni < 4; ++ni)
        acc[mi][ni] = __builtin_amdgcn_mfma_f32_16x16x32_f16(af[mi], bf[ni], acc[mi][ni], 0, 0, 0);
  }
#pragma unroll
  for (int mi = 0; mi < 4; ++mi)
#pragma unroll
    for (int ni = 0; ni < 4; ++ni) {
      size_t r0 = tm + wm * 64 + mi * 16 + quad * 4;
      size_t cc = tn + wn * 64 + ni * 16 + l15;
#pragma unroll
      for (int q = 0; q < 4; ++q) Cz_[(r0 + q) * G4z + cc] = acc[mi][ni][q];
    }
}

// ---------------- persistent LSTM: 16 WGs, slice HL by 16, spin barrier per step ----------------
__global__ void __launch_bounds__(128) k_lstm(const float* __restrict__ preS,
                                              const float* __restrict__ Whh,
                                              const float* __restrict__ bih,
                                              const float* __restrict__ bhh,
                                              float* __restrict__ hbuf,  // [2][32][256] fp32
                                              int* __restrict__ ctr,     // [64]
                                              float* __restrict__ hlast, // [32][256]
                                              int NS)
{
  __shared__ _Float16 Wt[64 * 264];   // 64 rows (4 gates x 16 hl), padded stride 264
  __shared__ _Float16 hs[32 * 264];   // h as fp16, padded
  __shared__ float bias_s[64];
  const int tid = threadIdx.x;
  const int w = blockIdx.x;  // hl slice [w*16, w*16+16)
  {
    int jr = tid >> 1, hh = tid & 1;
    int jglob = (jr >> 4) * HLz + w * 16 + (jr & 15);
    const float* srcp = Whh + (size_t)jglob * HLz + hh * 128;
    _Float16* dstp = &Wt[jr * 264 + hh * 128];
    for (int k = 0; k < 128; k += 4) {
      float4 v = *(const float4*)&srcp[k];
      dstp[k] = (_Float16)v.x; dstp[k + 1] = (_Float16)v.y;
      dstp[k + 2] = (_Float16)v.z; dstp[k + 3] = (_Float16)v.w;
    }
    if (tid < 64) {
      int jg = (tid >> 4) * HLz + w * 16 + (tid & 15);
      bias_s[tid] = bih[jg] + bhh[jg];
    }
  }
  const int lane = tid & 63, wave = tid >> 6;
  const int quad = lane >> 4, l15 = lane & 15;
  float cst[4] = {0.f, 0.f, 0.f, 0.f};
  __syncthreads();

  for (int t = 0; t < Tz; ++t) {
    const unsigned long long* hb =
        (const unsigned long long*)(hbuf + (size_t)(t & 1) * Bz * HLz);
    for (int i = tid; i < Bz * HLz / 2; i += 128) {
      unsigned long long u =
          __hip_atomic_load(hb + i, __ATOMIC_RELAXED, __HIP_MEMORY_SCOPE_AGENT);
      union { unsigned long long u64; float f[2]; } cv;
      cv.u64 = u;
      int flat = i * 2;
      int bb = flat >> 8, kk = flat & 255;
      half2v hv;
      hv.x = (_Float16)cv.f[0];
      hv.y = (_Float16)cv.f[1];
      *(half2v*)&hs[bb * 264 + kk] = hv;
    }
    __syncthreads();
    floatx4 acc[4] = {};
#pragma unroll
    for (int ks = 0; ks < 8; ++ks) {
      half8 a = *(const half8*)&hs[(wave * 16 + l15) * 264 + ks * 32 + quad * 8];
#pragma unroll
      for (int ni = 0; ni < 4; ++ni) {
        half8 b = *(const half8*)&Wt[(ni * 16 + l15) * 264 + ks * 32 + quad * 8];
        acc[ni] = __builtin_amdgcn_mfma_f32_16x16x32_f16(a, b, acc[ni], 0, 0, 0);
      }
    }
    float* hb_next = hbuf + (size_t)((t + 1) & 1) * Bz * HLz;
#pragma unroll
    for (int q = 0; q < 4; ++q) {
      int batch = wave * 16 + quad * 4 + q;
      int jc = w * 16 + l15;
      size_t prow = ((size_t)batch * Tz + t) * G4z;
      float pi = 0.f, pf = 0.f, pg = 0.f, po = 0.f;
      for (int s = 0; s < NS; ++s) {
        const float* ps = preS + (size_t)s * Mz * G4z + prow;
        pi += ps[jc]; pf += ps[256 + jc]; pg += ps[512 + jc]; po += ps[768 + jc];
      }
      float gi = acc[0][q] + pi + bias_s[l15];
      float gf = acc[1][q] + pf + bias_s[16 + l15];
      float gg = acc[2][q] + pg + bias_s[32 + l15];
      float go = acc[3][q] + po + bias_s[48 + l15];
      float iv = sigm(gi), fv = sigm(gf), gv = tanhh(gg), ov = sigm(go);
      float cn = fv * cst[q] + iv * gv;
      cst[q] = cn;
      float hn = ov * tanhh(cn);
      if (t < Tz - 1) {
        __hip_atomic_store(&hb_next[batch * HLz + jc], hn, __ATOMIC_RELAXED,
                           __HIP_MEMORY_SCOPE_AGENT);
      } else {
        hlast[batch * HLz + jc] = hn;
      }
    }
    if (t < Tz - 1) {
      __syncthreads();
      if (tid == 0) {
        __threadfence();
        __hip_atomic_fetch_add(&ctr[t], 1, __ATOMIC_RELEASE, __HIP_MEMORY_SCOPE_AGENT);
        while (__hip_atomic_load(&ctr[t], __ATOMIC_ACQUIRE, __HIP_MEMORY_SCOPE_AGENT) < 16)
          __builtin_amdgcn_s_sleep(2);
      }
      __syncthreads();
    }
  }
}

// out[b,o] = h_last[b,:] @ W_proj[o,:] + b_proj[o]
__global__ void k_proj(const float* __restrict__ hlast, const float* __restrict__ Wp,
                       const float* __restrict__ bp, float* __restrict__ out) {
  int idx = blockIdx.x * 256 + threadIdx.x;
  if (idx >= Bz * OUTz) return;
  int b = idx / OUTz, o = idx % OUTz;
  const float* h = hlast + (size_t)b * HLz;
  const float* wr = Wp + (size_t)o * HLz;
  float s = 0.f;
  for (int k = 0; k < HLz; k += 4) {
    float4 hv = *(const float4*)&h[k];
    float4 wv = *(const float4*)&wr[k];
    s += hv.x * wv.x + hv.y * wv.y + hv.z * wv.z + hv.w * wv.w;
  }
  out[idx] = s + bp[o];
}

extern "C" void kernel_launch(void* const* d_in, const int* in_sizes, int n_in,
                              void* d_out, int out_size, void* d_ws, size_t ws_size,
                              hipStream_t stream) {
  const float* x   = (const float*)d_in[0];
  const int*   ei  = (const int*)d_in[1];
  const float* ew  = (const float*)d_in[2];
  const float* Wg  = (const float*)d_in[3];
  const float* bg  = (const float*)d_in[4];
  const float* Wih = (const float*)d_in[5];
  const float* Whh = (const float*)d_in[6];
  const float* bih = (const float*)d_in[7];
  const float* bhh = (const float*)d_in[8];
  const float* Wp  = (const float*)d_in[9];
  const float* bp  = (const float*)d_in[10];
  float* out = (float*)d_out;
  char* ws = (char*)d_ws;

  // pick largest split count that fits the workspace
  int NS = 4;
  while (NS > 1 && OFF_PRES + (size_t)NS * SPLIT_BYTES > ws_size) NS >>= 1;
  if (OFF_PRES + (size_t)NS * SPLIT_BYTES > ws_size) return;  // hopeless

  float* deg   = (float*)(ws + OFF_DEG);
  float* ideg  = (float*)(ws + OFF_IDEG);
  float* norm  = (float*)(ws + OFF_NORM);
  int*   cnt   = (int*)(ws + OFF_CNT);
  int*   roff  = (int*)(ws + OFF_ROFF);
  int*   cur   = (int*)(ws + OFF_CUR);
  int*   csrs  = (int*)(ws + OFF_CSRS);
  float* csrw  = (float*)(ws + OFF_CSRW);
  float* hbuf  = (float*)(ws + OFF_HBUF);
  float* hlast = (float*)(ws + OFF_HLAST);
  int*   ctr   = (int*)(ws + OFF_CTR);
  _Float16* seq16 = (_Float16*)(ws + OFF_SEQ);
  _Float16* wih16 = (_Float16*)(ws + OFF_WIH);
  float* preS  = (float*)(ws + OFF_PRES);

  hipMemsetAsync(ws + OFF_CNT, 0, 4096, stream);
  hipMemsetAsync(ws + OFF_HBUF, 0, OFF_SEQ - OFF_HBUF, stream);

  k_deg_init<<<4, 256, 0, stream>>>(deg);
  k_deg_scatter<<<63, 256, 0, stream>>>(ei, ew, deg);
  k_norm<<<63, 256, 0, stream>>>(ei, ew, deg, norm, ideg);
  k_csr_count<<<63, 256, 0, stream>>>(ei, cnt);
  k_scan<<<1, 1024, 0, stream>>>(cnt, roff, cur);
  k_csr_fill<<<63, 256, 0, stream>>>(ei, norm, cur, csrs, csrw);
  k_f32tof16<<<8000, 256, 0, stream>>>(Wih, wih16, (size_t)G4z * Kz / 8);
  k_seq<<<8000, 256, 0, stream>>>(x, Wg, bg, ideg, seq16);
  k_aggseq<<<1000, 256, 0, stream>>>(x, Wg, roff, cnt, csrs, csrw, seq16);
  k_gemm<<<dim3(16, 8, NS), 256, 0, stream>>>(seq16, wih16, preS, Kz / NS, Kz / NS / 32);
  k_lstm<<<16, 128, 0, stream>>>(preS, Whh, bih, bhh, hbuf, ctr, hlast, NS);
  k_proj<<<3, 256, 0, stream>>>(hlast, Wp, bp, out);
}

// Round 3
// 927.680 us; speedup vs baseline: 2.1639x; 1.5209x over previous
//
#include <hip/hip_runtime.h>
#include <stdint.h>

// Problem constants
#define Bz 32
#define Tz 64
#define Nz 1000
#define Cz 8
#define HGz 16
#define HLz 256
#define OUTz 24
#define Ez 16000
#define Kz 16000   // N*HG
#define Mz 2048    // B*T
#define G4z 1024   // 4*HL

using half8  = __attribute__((ext_vector_type(8))) _Float16;
using half4  = __attribute__((ext_vector_type(4))) _Float16;
using floatx4 = __attribute__((ext_vector_type(4))) float;

// ---- Workspace layout (bytes) ----
static const size_t OFF_DEG    = 0;         // fp32 [1000]
static const size_t OFF_IDEG   = 4096;      // fp32 [1000]
static const size_t OFF_NORM   = 8192;      // fp32 [16000]
static const size_t OFF_CNT    = 73728;     // int  [1024]
static const size_t OFF_ROFF   = 77824;     // int  [1024]
static const size_t OFF_CUR    = 81920;     // int  [1024]
static const size_t OFF_CSRS   = 86016;     // int  [16000]
static const size_t OFF_CSRW   = 151552;    // fp32 [16000]
static const size_t OFF_HLAST  = 217088;    // fp32 [32][256]
static const size_t OFF_PRE16T = 249856;    // fp16 [64][1024][32]  4,194,304
static const size_t OFF_WHH16  = 4444160;   // fp16 [1024][256]       524,288
static const size_t OFF_SEQ    = 4968448;   // fp16 [2048][16000]  65,536,000
static const size_t OFF_WIH    = 70504448;  // fp16 [1024][16000]  32,768,000
static const size_t OFF_PRES   = 103272448; // fp32 [NS][2048][1024]
static const size_t SPLIT_BYTES = 8388608;

__device__ __forceinline__ void gl_lds16(const void* g, void* l) {
  __builtin_amdgcn_global_load_lds(
      (__attribute__((address_space(1))) void*)(void*)g,
      (__attribute__((address_space(3))) void*)l, 16, 0, 0);
}

__device__ __forceinline__ float sigm(float x) { return 1.0f / (1.0f + __expf(-x)); }
__device__ __forceinline__ float tanhh(float x) { return 1.0f - 2.0f / (__expf(2.0f * x) + 1.0f); }

// ---------------- GCN prep ----------------
__global__ void k_deg_init(float* deg) {
  int i = blockIdx.x * 256 + threadIdx.x;
  if (i < Nz) deg[i] = 1.0f;
}

__global__ void k_deg_scatter(const int* __restrict__ ei, const float* __restrict__ ew,
                              float* deg) {
  int e = blockIdx.x * 256 + threadIdx.x;
  if (e < Ez) atomicAdd(&deg[ei[Ez + e]], ew[e]);
}

__global__ void k_norm(const int* __restrict__ ei, const float* __restrict__ ew,
                       const float* __restrict__ deg, float* __restrict__ norm,
                       float* __restrict__ ideg) {
  int e = blockIdx.x * 256 + threadIdx.x;
  if (e < Ez) {
    float dr = deg[ei[e]], dc = deg[ei[Ez + e]];
    norm[e] = ew[e] * (1.0f / sqrtf(dr)) * (1.0f / sqrtf(dc));
  }
  if (e < Nz) ideg[e] = 1.0f / deg[e];
}

__global__ void k_csr_count(const int* __restrict__ ei, int* __restrict__ cnt) {
  int e = blockIdx.x * 256 + threadIdx.x;
  if (e < Ez) atomicAdd(&cnt[ei[Ez + e]], 1);
}

__global__ void k_scan(const int* __restrict__ cnt, int* __restrict__ roff,
                       int* __restrict__ cur) {
  __shared__ int s[1024];
  int tid = threadIdx.x;
  int v0 = cnt[tid];
  s[tid] = v0;
  __syncthreads();
  for (int off = 1; off < 1024; off <<= 1) {
    int v = (tid >= off) ? s[tid - off] : 0;
    __syncthreads();
    s[tid] += v;
    __syncthreads();
  }
  int excl = s[tid] - v0;
  roff[tid] = excl;
  cur[tid] = excl;
}

__global__ void k_csr_fill(const int* __restrict__ ei, const float* __restrict__ norm,
                           int* __restrict__ cur, int* __restrict__ csrs,
                           float* __restrict__ csrw) {
  int e = blockIdx.x * 256 + threadIdx.x;
  if (e >= Ez) return;
  int dst = ei[Ez + e];
  int p = atomicAdd(&cur[dst], 1);
  csrs[p] = ei[e];
  csrw[p] = norm[e];
}

// fp32 -> fp16 bulk convert (8 elems/thread)
__global__ void k_f32tof16(const float* __restrict__ src, _Float16* __restrict__ dst,
                           size_t n8) {
  size_t i = (size_t)blockIdx.x * 256 + threadIdx.x;
  if (i >= n8) return;
  float4 a = ((const float4*)src)[i * 2];
  float4 b = ((const float4*)src)[i * 2 + 1];
  half8 h;
  h[0] = (_Float16)a.x; h[1] = (_Float16)a.y; h[2] = (_Float16)a.z; h[3] = (_Float16)a.w;
  h[4] = (_Float16)b.x; h[5] = (_Float16)b.y; h[6] = (_Float16)b.z; h[7] = (_Float16)b.w;
  ((half8*)dst)[i] = h;
}

// seq[bt, n*16+h] = fp16( xw (*ideg for batch0) + b_gcn )
__global__ void k_seq(const float* __restrict__ x, const float* __restrict__ Wg,
                      const float* __restrict__ bg, const float* __restrict__ ideg,
                      _Float16* __restrict__ seq) {
  __shared__ float wgs[Cz * HGz];
  __shared__ float bgs[HGz];
  if (threadIdx.x < Cz * HGz) wgs[threadIdx.x] = Wg[threadIdx.x];
  if (threadIdx.x < HGz) bgs[threadIdx.x] = bg[threadIdx.x];
  __syncthreads();
  int idx = blockIdx.x * 256 + threadIdx.x;
  if (idx >= Mz * Nz) return;
  int n = idx % Nz;
  int bt = idx / Nz;
  const float* xp = x + (size_t)idx * Cz;
  float4 v0 = *(const float4*)xp, v1 = *(const float4*)(xp + 4);
  float xv[8] = {v0.x, v0.y, v0.z, v0.w, v1.x, v1.y, v1.z, v1.w};
  float s[HGz];
#pragma unroll
  for (int h = 0; h < HGz; ++h) {
    float a = 0.f;
#pragma unroll
    for (int c = 0; c < Cz; ++c) a += xv[c] * wgs[c * HGz + h];
    s[h] = a;
  }
  float id = (bt < Tz) ? ideg[n] : 1.0f;
#pragma unroll
  for (int h = 0; h < HGz; ++h) s[h] = s[h] * id + bgs[h];
  half8 h0, h1;
#pragma unroll
  for (int j = 0; j < 8; ++j) { h0[j] = (_Float16)s[j]; h1[j] = (_Float16)s[8 + j]; }
  half8* op = (half8*)(seq + (size_t)bt * Kz + n * HGz);
  op[0] = h0;
  op[1] = h1;
}

// Neighbor aggregation for batch 0, CSR gather, fused x@W_gcn, RMW into seq fp16.
__global__ void k_aggseq(const float* __restrict__ x, const float* __restrict__ Wg,
                         const int* __restrict__ roff, const int* __restrict__ cnt,
                         const int* __restrict__ csrs, const float* __restrict__ csrw,
                         _Float16* __restrict__ seq) {
  __shared__ float wgs[Cz * HGz];
  if (threadIdx.x < Cz * HGz) wgs[threadIdx.x] = Wg[threadIdx.x];
  __syncthreads();
  int g = blockIdx.x * 256 + threadIdx.x;
  if (g >= Tz * Nz * 4) return;
  int t = g / (Nz * 4);
  int r = g % (Nz * 4);
  int n = r >> 2;
  int hq = r & 3;
  int nc = cnt[n];
  if (nc == 0) return;
  float w0[Cz], w1[Cz], w2[Cz], w3[Cz];
#pragma unroll
  for (int c = 0; c < Cz; ++c) {
    w0[c] = wgs[c * HGz + hq * 4 + 0];
    w1[c] = wgs[c * HGz + hq * 4 + 1];
    w2[c] = wgs[c * HGz + hq * 4 + 2];
    w3[c] = wgs[c * HGz + hq * 4 + 3];
  }
  float s0 = 0.f, s1 = 0.f, s2 = 0.f, s3 = 0.f;
  int i0 = roff[n];
  for (int i = i0; i < i0 + nc; ++i) {
    int src = csrs[i];
    float wv = csrw[i];
    const float* xp = x + ((size_t)t * Nz + src) * Cz;
    float4 a = *(const float4*)xp;
    float4 b = *(const float4*)(xp + 4);
    float xv[8] = {a.x, a.y, a.z, a.w, b.x, b.y, b.z, b.w};
    float m0 = 0.f, m1 = 0.f, m2 = 0.f, m3 = 0.f;
#pragma unroll
    for (int c = 0; c < Cz; ++c) {
      m0 += xv[c] * w0[c];
      m1 += xv[c] * w1[c];
      m2 += xv[c] * w2[c];
      m3 += xv[c] * w3[c];
    }
    s0 += wv * m0; s1 += wv * m1; s2 += wv * m2; s3 += wv * m3;
  }
  half4* p = (half4*)(seq + (size_t)t * Kz + n * HGz + hq * 4);
  half4 hv = *p;
  hv[0] = (_Float16)((float)hv[0] + s0);
  hv[1] = (_Float16)((float)hv[1] + s1);
  hv[2] = (_Float16)((float)hv[2] + s2);
  hv[3] = (_Float16)((float)hv[3] + s3);
  *p = hv;
}

// ---------------- big GEMM: preS[z][2048][1024] = seq @ W_ih^T (split-K, plain stores) ----------------
__global__ void __launch_bounds__(256) k_gemm(const _Float16* __restrict__ A,
                                              const _Float16* __restrict__ Bm,
                                              float* __restrict__ Cp,
                                              int kLen, int iters) {
  __shared__ _Float16 As[128 * 32];
  __shared__ _Float16 Bs[128 * 32];
  const int tid = threadIdx.x;
  const int lane = tid & 63;
  const int wave = tid >> 6;
  const int wm = wave & 1, wn = wave >> 1;
  const int quad = lane >> 4, l15 = lane & 15;
  const size_t tm = (size_t)blockIdx.x * 128;
  const size_t tn = (size_t)blockIdx.y * 128;
  const int k0 = blockIdx.z * kLen;
  float* Cz_ = Cp + (size_t)blockIdx.z * Mz * G4z;
  const int srow = tid >> 2;
  const int skk = (tid & 3) * 8;
  const _Float16* gA0 = A + (tm + srow) * (size_t)Kz + k0 + skk;
  const _Float16* gA1 = gA0 + 64 * (size_t)Kz;
  const _Float16* gB0 = Bm + (tn + srow) * (size_t)Kz + k0 + skk;
  const _Float16* gB1 = gB0 + 64 * (size_t)Kz;
  _Float16* lA0 = &As[tid * 8];
  _Float16* lA1 = &As[2048 + tid * 8];
  _Float16* lB0 = &Bs[tid * 8];
  _Float16* lB1 = &Bs[2048 + tid * 8];
  floatx4 acc[4][4] = {};
  for (int kt = 0; kt < iters; ++kt) {
    __syncthreads();
    gl_lds16(gA0, lA0);
    gl_lds16(gA1, lA1);
    gl_lds16(gB0, lB0);
    gl_lds16(gB1, lB1);
    gA0 += 32; gA1 += 32; gB0 += 32; gB1 += 32;
    __syncthreads();
    half8 af[4], bf[4];
#pragma unroll
    for (int i = 0; i < 4; ++i)
      af[i] = *(const half8*)&As[(wm * 64 + i * 16 + l15) * 32 + quad * 8];
#pragma unroll
    for (int i = 0; i < 4; ++i)
      bf[i] = *(const half8*)&Bs[(wn * 64 + i * 16 + l15) * 32 + quad * 8];
#pragma unroll
    for (int mi = 0; mi < 4; ++mi)
#pragma unroll
      for (int ni = 0; ni < 4; ++ni)
        acc[mi][ni] = __builtin_amdgcn_mfma_f32_16x16x32_f16(af[mi], bf[ni], acc[mi][ni], 0, 0, 0);
  }
#pragma unroll
  for (int mi = 0; mi < 4; ++mi)
#pragma unroll
    for (int ni = 0; ni < 4; ++ni) {
      size_t r0 = tm + wm * 64 + mi * 16 + quad * 4;
      size_t cc = tn + wn * 64 + ni * 16 + l15;
#pragma unroll
      for (int q = 0; q < 4; ++q) Cz_[(r0 + q) * G4z + cc] = acc[mi][ni][q];
    }
}

// ---------------- reduce split-K + bias -> transposed fp16 pre[t][j][batch] ----------------
__global__ void k_reduce(const float* __restrict__ preS, const float* __restrict__ bih,
                         const float* __restrict__ bhh, _Float16* __restrict__ preT,
                         int NS) {
  int t = blockIdx.x;                 // 0..63
  int j = blockIdx.y * 256 + threadIdx.x;  // 0..1023
  float bias = bih[j] + bhh[j];
  float v[32];
#pragma unroll
  for (int b = 0; b < 32; ++b) v[b] = bias;
  for (int s = 0; s < NS; ++s) {
    const float* base = preS + (size_t)s * Mz * G4z;
#pragma unroll
    for (int b = 0; b < 32; ++b)
      v[b] += base[((size_t)b * Tz + t) * G4z + j];
  }
  half8 h[4];
#pragma unroll
  for (int i = 0; i < 32; ++i) ((_Float16*)h)[i] = (_Float16)v[i];
  half8* op = (half8*)(preT + ((size_t)t * G4z + j) * Bz);
#pragma unroll
  for (int i = 0; i < 4; ++i) op[i] = h[i];
}

// ---------------- LSTM: batch-split, no inter-WG communication. ----------------
// 8 WGs x 512 threads; WG bg owns batches [bg*4, bg*4+4). Each wave (8/WG) owns
// hl slices [wv*16,wv*16+16) and [128+wv*16, 128+wv*16+16) across all 4 gates,
// streaming its W_hh rows from L2 every step (512 KB/CU/step). h exchange via LDS only.
__global__ void __launch_bounds__(512, 2) k_lstm2(const _Float16* __restrict__ Whh16,
                                                  const _Float16* __restrict__ preT,
                                                  float* __restrict__ hlast) {
  __shared__ _Float16 hs[2][16 * 264];  // h fp16, A-frag layout, padded stride 264
  const int tid = threadIdx.x;
  const int bg = blockIdx.x;           // batch group
  const int wv = tid >> 6;
  const int lane = tid & 63;
  const int quad = lane >> 4, l15 = lane & 15;
  for (int i = tid; i < 2 * 16 * 264; i += 512) ((_Float16*)hs)[i] = (_Float16)0.f;
  // W fragment bases: f = g*2+blk -> rows j = (g*16 + blk*8 + wv)*16 + l15
  const _Float16* wbase[8];
#pragma unroll
  for (int g = 0; g < 4; ++g)
#pragma unroll
    for (int blk = 0; blk < 2; ++blk) {
      int jg = g * 16 + blk * 8 + wv;
      wbase[g * 2 + blk] = Whh16 + ((size_t)(jg * 16 + l15)) * HLz + quad * 8;
    }
  float cst[2][4] = {};
  __syncthreads();
  half8 wf[2][8];
  for (int t = 0; t < Tz; ++t) {
    // pre loads for this step (lanes 0..15 hold the C-layout outputs)
    half4 preq[8];
    if (lane < 16) {
#pragma unroll
      for (int f = 0; f < 8; ++f) {
        int g = f >> 1, blk = f & 1;
        int j = (g * 16 + blk * 8 + wv) * 16 + l15;
        preq[f] = *(const half4*)(preT + ((size_t)t * G4z + j) * Bz + bg * 4);
      }
    }
    // preload kt=0 W frags
#pragma unroll
    for (int f = 0; f < 8; ++f) wf[0][f] = *(const half8*)(wbase[f]);
    floatx4 acc[8] = {};
    const _Float16* hrow = &hs[t & 1][l15 * 264 + quad * 8];
#pragma unroll
    for (int kt = 0; kt < 8; ++kt) {
      if (kt < 7) {
#pragma unroll
        for (int f = 0; f < 8; ++f)
          wf[(kt + 1) & 1][f] = *(const half8*)(wbase[f] + (kt + 1) * 32);
      }
      half8 a = *(const half8*)(hrow + kt * 32);
#pragma unroll
      for (int f = 0; f < 8; ++f)
        acc[f] = __builtin_amdgcn_mfma_f32_16x16x32_f16(a, wf[kt & 1][f], acc[f], 0, 0, 0);
    }
    _Float16* hnext = &hs[(t + 1) & 1][0];
    if (lane < 16) {
#pragma unroll
      for (int blk = 0; blk < 2; ++blk) {
        int hl = blk * 128 + wv * 16 + l15;
#pragma unroll
        for (int q = 0; q < 4; ++q) {
          float gi = acc[0 + blk][q] + (float)preq[0 + blk][q];
          float gf = acc[2 + blk][q] + (float)preq[2 + blk][q];
          float gg = acc[4 + blk][q] + (float)preq[4 + blk][q];
          float go = acc[6 + blk][q] + (float)preq[6 + blk][q];
          float iv = sigm(gi), fv = sigm(gf), gv = tanhh(gg), ov = sigm(go);
          float cn = fv * cst[blk][q] + iv * gv;
          cst[blk][q] = cn;
          float hn = ov * tanhh(cn);
          if (t < Tz - 1) hnext[q * 264 + hl] = (_Float16)hn;
          else hlast[(size_t)(bg * 4 + q) * HLz + hl] = hn;
        }
      }
    }
    __syncthreads();
  }
}

// out[b,o] = h_last[b,:] @ W_proj[o,:] + b_proj[o]
__global__ void k_proj(const float* __restrict__ hlast, const float* __restrict__ Wp,
                       const float* __restrict__ bp, float* __restrict__ out) {
  int idx = blockIdx.x * 256 + threadIdx.x;
  if (idx >= Bz * OUTz) return;
  int b = idx / OUTz, o = idx % OUTz;
  const float* h = hlast + (size_t)b * HLz;
  const float* wr = Wp + (size_t)o * HLz;
  float s = 0.f;
  for (int k = 0; k < HLz; k += 4) {
    float4 hv = *(const float4*)&h[k];
    float4 wv = *(const float4*)&wr[k];
    s += hv.x * wv.x + hv.y * wv.y + hv.z * wv.z + hv.w * wv.w;
  }
  out[idx] = s + bp[o];
}

extern "C" void kernel_launch(void* const* d_in, const int* in_sizes, int n_in,
                              void* d_out, int out_size, void* d_ws, size_t ws_size,
                              hipStream_t stream) {
  const float* x   = (const float*)d_in[0];
  const int*   ei  = (const int*)d_in[1];
  const float* ew  = (const float*)d_in[2];
  const float* Wg  = (const float*)d_in[3];
  const float* bg  = (const float*)d_in[4];
  const float* Wih = (const float*)d_in[5];
  const float* Whh = (const float*)d_in[6];
  const float* bih = (const float*)d_in[7];
  const float* bhh = (const float*)d_in[8];
  const float* Wp  = (const float*)d_in[9];
  const float* bp  = (const float*)d_in[10];
  float* out = (float*)d_out;
  char* ws = (char*)d_ws;

  int NS = 4;
  while (NS > 1 && OFF_PRES + (size_t)NS * SPLIT_BYTES > ws_size) NS >>= 1;
  if (OFF_PRES + (size_t)NS * SPLIT_BYTES > ws_size) return;

  float* deg   = (float*)(ws + OFF_DEG);
  float* ideg  = (float*)(ws + OFF_IDEG);
  float* norm  = (float*)(ws + OFF_NORM);
  int*   cnt   = (int*)(ws + OFF_CNT);
  int*   roff  = (int*)(ws + OFF_ROFF);
  int*   cur   = (int*)(ws + OFF_CUR);
  int*   csrs  = (int*)(ws + OFF_CSRS);
  float* csrw  = (float*)(ws + OFF_CSRW);
  float* hlast = (float*)(ws + OFF_HLAST);
  _Float16* preT  = (_Float16*)(ws + OFF_PRE16T);
  _Float16* whh16 = (_Float16*)(ws + OFF_WHH16);
  _Float16* seq16 = (_Float16*)(ws + OFF_SEQ);
  _Float16* wih16 = (_Float16*)(ws + OFF_WIH);
  float* preS  = (float*)(ws + OFF_PRES);

  hipMemsetAsync(ws + OFF_CNT, 0, 4096, stream);

  k_deg_init<<<4, 256, 0, stream>>>(deg);
  k_deg_scatter<<<63, 256, 0, stream>>>(ei, ew, deg);
  k_norm<<<63, 256, 0, stream>>>(ei, ew, deg, norm, ideg);
  k_csr_count<<<63, 256, 0, stream>>>(ei, cnt);
  k_scan<<<1, 1024, 0, stream>>>(cnt, roff, cur);
  k_csr_fill<<<63, 256, 0, stream>>>(ei, norm, cur, csrs, csrw);
  k_f32tof16<<<8000, 256, 0, stream>>>(Wih, wih16, (size_t)G4z * Kz / 8);
  k_f32tof16<<<128, 256, 0, stream>>>(Whh, whh16, (size_t)G4z * HLz / 8);
  k_seq<<<8000, 256, 0, stream>>>(x, Wg, bg, ideg, seq16);
  k_aggseq<<<1000, 256, 0, stream>>>(x, Wg, roff, cnt, csrs, csrw, seq16);
  k_gemm<<<dim3(16, 8, NS), 256, 0, stream>>>(seq16, wih16, preS, Kz / NS, Kz / NS / 32);
  k_reduce<<<dim3(Tz, 4), 256, 0, stream>>>(preS, bih, bhh, preT, NS);
  k_lstm2<<<8, 512, 0, stream>>>(whh16, preT, hlast);
  k_proj<<<3, 256, 0, stream>>>(hlast, Wp, bp, out);
}

// Round 4
// 605.756 us; speedup vs baseline: 3.3139x; 1.5314x over previous
//
#include <hip/hip_runtime.h>
#include <stdint.h>

// Problem constants
#define Bz 32
#define Tz 64
#define Nz 1000
#define Cz 8
#define HGz 16
#define HLz 256
#define OUTz 24
#define Ez 16000
#define Kz 16000   // N*HG
#define Mz 2048    // B*T
#define G4z 1024   // 4*HL

using half8  = __attribute__((ext_vector_type(8))) _Float16;
using half4  = __attribute__((ext_vector_type(4))) _Float16;
using floatx4 = __attribute__((ext_vector_type(4))) float;

// ---- Workspace layout (bytes) ----
static const size_t OFF_DEG    = 0;         // fp32 [1000]
static const size_t OFF_IDEG   = 4096;      // fp32 [1000]
static const size_t OFF_NORM   = 8192;      // fp32 [16000]
static const size_t OFF_CNT    = 73728;     // int  [1024]
static const size_t OFF_ROFF   = 77824;     // int  [1024]
static const size_t OFF_CUR    = 81920;     // int  [1024]
static const size_t OFF_CSRS   = 86016;     // int  [16000]
static const size_t OFF_CSRW   = 151552;    // fp32 [16000]
static const size_t OFF_HLAST  = 217088;    // fp32 [32][256]
static const size_t OFF_PRE16T = 249856;    // fp16 [64][1024][32]  4,194,304
static const size_t OFF_WHH16  = 4444160;   // fp16 [1024][256]       524,288
static const size_t OFF_HX     = 4968448;   // fp16 [8][65][4][256] 1,064,960
static const size_t OFF_CTR2   = 6033408;   // int  [8*65]              4096
static const size_t OFF_SEQ    = 6037504;   // fp16 [2048][16000]  65,536,000
static const size_t OFF_WIH    = 71573504;  // fp16 [1024][16000]  32,768,000
static const size_t OFF_PRES   = 104341504; // fp32 [NS][2048][1024]
static const size_t SPLIT_BYTES = 8388608;

__device__ __forceinline__ void gl_lds16(const void* g, void* l) {
  __builtin_amdgcn_global_load_lds(
      (__attribute__((address_space(1))) void*)(void*)g,
      (__attribute__((address_space(3))) void*)l, 16, 0, 0);
}

__device__ __forceinline__ float sigm(float x) { return 1.0f / (1.0f + __expf(-x)); }
__device__ __forceinline__ float tanhh(float x) { return 1.0f - 2.0f / (__expf(2.0f * x) + 1.0f); }

// ---------------- GCN prep ----------------
__global__ void k_deg_init(float* deg) {
  int i = blockIdx.x * 256 + threadIdx.x;
  if (i < Nz) deg[i] = 1.0f;
}

__global__ void k_deg_scatter(const int* __restrict__ ei, const float* __restrict__ ew,
                              float* deg) {
  int e = blockIdx.x * 256 + threadIdx.x;
  if (e < Ez) atomicAdd(&deg[ei[Ez + e]], ew[e]);
}

__global__ void k_norm(const int* __restrict__ ei, const float* __restrict__ ew,
                       const float* __restrict__ deg, float* __restrict__ norm,
                       float* __restrict__ ideg) {
  int e = blockIdx.x * 256 + threadIdx.x;
  if (e < Ez) {
    float dr = deg[ei[e]], dc = deg[ei[Ez + e]];
    norm[e] = ew[e] * (1.0f / sqrtf(dr)) * (1.0f / sqrtf(dc));
  }
  if (e < Nz) ideg[e] = 1.0f / deg[e];
}

__global__ void k_csr_count(const int* __restrict__ ei, int* __restrict__ cnt) {
  int e = blockIdx.x * 256 + threadIdx.x;
  if (e < Ez) atomicAdd(&cnt[ei[Ez + e]], 1);
}

__global__ void k_scan(const int* __restrict__ cnt, int* __restrict__ roff,
                       int* __restrict__ cur) {
  __shared__ int s[1024];
  int tid = threadIdx.x;
  int v0 = cnt[tid];
  s[tid] = v0;
  __syncthreads();
  for (int off = 1; off < 1024; off <<= 1) {
    int v = (tid >= off) ? s[tid - off] : 0;
    __syncthreads();
    s[tid] += v;
    __syncthreads();
  }
  int excl = s[tid] - v0;
  roff[tid] = excl;
  cur[tid] = excl;
}

__global__ void k_csr_fill(const int* __restrict__ ei, const float* __restrict__ norm,
                           int* __restrict__ cur, int* __restrict__ csrs,
                           float* __restrict__ csrw) {
  int e = blockIdx.x * 256 + threadIdx.x;
  if (e >= Ez) return;
  int dst = ei[Ez + e];
  int p = atomicAdd(&cur[dst], 1);
  csrs[p] = ei[e];
  csrw[p] = norm[e];
}

// fp32 -> fp16 bulk convert (8 elems/thread)
__global__ void k_f32tof16(const float* __restrict__ src, _Float16* __restrict__ dst,
                           size_t n8) {
  size_t i = (size_t)blockIdx.x * 256 + threadIdx.x;
  if (i >= n8) return;
  float4 a = ((const float4*)src)[i * 2];
  float4 b = ((const float4*)src)[i * 2 + 1];
  half8 h;
  h[0] = (_Float16)a.x; h[1] = (_Float16)a.y; h[2] = (_Float16)a.z; h[3] = (_Float16)a.w;
  h[4] = (_Float16)b.x; h[5] = (_Float16)b.y; h[6] = (_Float16)b.z; h[7] = (_Float16)b.w;
  ((half8*)dst)[i] = h;
}

// seq[bt, n*16+h] = fp16( xw (*ideg for batch0) + b_gcn )
__global__ void k_seq(const float* __restrict__ x, const float* __restrict__ Wg,
                      const float* __restrict__ bg, const float* __restrict__ ideg,
                      _Float16* __restrict__ seq) {
  __shared__ float wgs[Cz * HGz];
  __shared__ float bgs[HGz];
  if (threadIdx.x < Cz * HGz) wgs[threadIdx.x] = Wg[threadIdx.x];
  if (threadIdx.x < HGz) bgs[threadIdx.x] = bg[threadIdx.x];
  __syncthreads();
  int idx = blockIdx.x * 256 + threadIdx.x;
  if (idx >= Mz * Nz) return;
  int n = idx % Nz;
  int bt = idx / Nz;
  const float* xp = x + (size_t)idx * Cz;
  float4 v0 = *(const float4*)xp, v1 = *(const float4*)(xp + 4);
  float xv[8] = {v0.x, v0.y, v0.z, v0.w, v1.x, v1.y, v1.z, v1.w};
  float s[HGz];
#pragma unroll
  for (int h = 0; h < HGz; ++h) {
    float a = 0.f;
#pragma unroll
    for (int c = 0; c < Cz; ++c) a += xv[c] * wgs[c * HGz + h];
    s[h] = a;
  }
  float id = (bt < Tz) ? ideg[n] : 1.0f;
#pragma unroll
  for (int h = 0; h < HGz; ++h) s[h] = s[h] * id + bgs[h];
  half8 h0, h1;
#pragma unroll
  for (int j = 0; j < 8; ++j) { h0[j] = (_Float16)s[j]; h1[j] = (_Float16)s[8 + j]; }
  half8* op = (half8*)(seq + (size_t)bt * Kz + n * HGz);
  op[0] = h0;
  op[1] = h1;
}

// Neighbor aggregation for batch 0, CSR gather, fused x@W_gcn, RMW into seq fp16.
__global__ void k_aggseq(const float* __restrict__ x, const float* __restrict__ Wg,
                         const int* __restrict__ roff, const int* __restrict__ cnt,
                         const int* __restrict__ csrs, const float* __restrict__ csrw,
                         _Float16* __restrict__ seq) {
  __shared__ float wgs[Cz * HGz];
  if (threadIdx.x < Cz * HGz) wgs[threadIdx.x] = Wg[threadIdx.x];
  __syncthreads();
  int g = blockIdx.x * 256 + threadIdx.x;
  if (g >= Tz * Nz * 4) return;
  int t = g / (Nz * 4);
  int r = g % (Nz * 4);
  int n = r >> 2;
  int hq = r & 3;
  int nc = cnt[n];
  if (nc == 0) return;
  float w0[Cz], w1[Cz], w2[Cz], w3[Cz];
#pragma unroll
  for (int c = 0; c < Cz; ++c) {
    w0[c] = wgs[c * HGz + hq * 4 + 0];
    w1[c] = wgs[c * HGz + hq * 4 + 1];
    w2[c] = wgs[c * HGz + hq * 4 + 2];
    w3[c] = wgs[c * HGz + hq * 4 + 3];
  }
  float s0 = 0.f, s1 = 0.f, s2 = 0.f, s3 = 0.f;
  int i0 = roff[n];
  for (int i = i0; i < i0 + nc; ++i) {
    int src = csrs[i];
    float wv = csrw[i];
    const float* xp = x + ((size_t)t * Nz + src) * Cz;
    float4 a = *(const float4*)xp;
    float4 b = *(const float4*)(xp + 4);
    float xv[8] = {a.x, a.y, a.z, a.w, b.x, b.y, b.z, b.w};
    float m0 = 0.f, m1 = 0.f, m2 = 0.f, m3 = 0.f;
#pragma unroll
    for (int c = 0; c < Cz; ++c) {
      m0 += xv[c] * w0[c];
      m1 += xv[c] * w1[c];
      m2 += xv[c] * w2[c];
      m3 += xv[c] * w3[c];
    }
    s0 += wv * m0; s1 += wv * m1; s2 += wv * m2; s3 += wv * m3;
  }
  half4* p = (half4*)(seq + (size_t)t * Kz + n * HGz + hq * 4);
  half4 hv = *p;
  hv[0] = (_Float16)((float)hv[0] + s0);
  hv[1] = (_Float16)((float)hv[1] + s1);
  hv[2] = (_Float16)((float)hv[2] + s2);
  hv[3] = (_Float16)((float)hv[3] + s3);
  *p = hv;
}

// ---------------- big GEMM: preS[z][2048][1024] = seq @ W_ih^T (split-K, plain stores) ----------------
__global__ void __launch_bounds__(256) k_gemm(const _Float16* __restrict__ A,
                                              const _Float16* __restrict__ Bm,
                                              float* __restrict__ Cp,
                                              int kLen, int iters) {
  __shared__ _Float16 As[128 * 32];
  __shared__ _Float16 Bs[128 * 32];
  const int tid = threadIdx.x;
  const int lane = tid & 63;
  const int wave = tid >> 6;
  const int wm = wave & 1, wn = wave >> 1;
  const int quad = lane >> 4, l15 = lane & 15;
  const size_t tm = (size_t)blockIdx.x * 128;
  const size_t tn = (size_t)blockIdx.y * 128;
  const int k0 = blockIdx.z * kLen;
  float* Cz_ = Cp + (size_t)blockIdx.z * Mz * G4z;
  const int srow = tid >> 2;
  const int skk = (tid & 3) * 8;
  const _Float16* gA0 = A + (tm + srow) * (size_t)Kz + k0 + skk;
  const _Float16* gA1 = gA0 + 64 * (size_t)Kz;
  const _Float16* gB0 = Bm + (tn + srow) * (size_t)Kz + k0 + skk;
  const _Float16* gB1 = gB0 + 64 * (size_t)Kz;
  _Float16* lA0 = &As[tid * 8];
  _Float16* lA1 = &As[2048 + tid * 8];
  _Float16* lB0 = &Bs[tid * 8];
  _Float16* lB1 = &Bs[2048 + tid * 8];
  floatx4 acc[4][4] = {};
  for (int kt = 0; kt < iters; ++kt) {
    __syncthreads();
    gl_lds16(gA0, lA0);
    gl_lds16(gA1, lA1);
    gl_lds16(gB0, lB0);
    gl_lds16(gB1, lB1);
    gA0 += 32; gA1 += 32; gB0 += 32; gB1 += 32;
    __syncthreads();
    half8 af[4], bf[4];
#pragma unroll
    for (int i = 0; i < 4; ++i)
      af[i] = *(const half8*)&As[(wm * 64 + i * 16 + l15) * 32 + quad * 8];
#pragma unroll
    for (int i = 0; i < 4; ++i)
      bf[i] = *(const half8*)&Bs[(wn * 64 + i * 16 + l15) * 32 + quad * 8];
#pragma unroll
    for (int mi = 0; mi < 4; ++mi)
#pragma unroll
      for (int ni = 0; ni < 4; ++ni)
        acc[mi][ni] = __builtin_amdgcn_mfma_f32_16x16x32_f16(af[mi], bf[ni], acc[mi][ni], 0, 0, 0);
  }
#pragma unroll
  for (int mi = 0; mi < 4; ++mi)
#pragma unroll
    for (int ni = 0; ni < 4; ++ni) {
      size_t r0 = tm + wm * 64 + mi * 16 + quad * 4;
      size_t cc = tn + wn * 64 + ni * 16 + l15;
#pragma unroll
      for (int q = 0; q < 4; ++q) Cz_[(r0 + q) * G4z + cc] = acc[mi][ni][q];
    }
}

// ---------------- reduce split-K + bias -> transposed fp16 pre[t][j][batch] ----------------
__global__ void k_reduce(const float* __restrict__ preS, const float* __restrict__ bih,
                         const float* __restrict__ bhh, _Float16* __restrict__ preT,
                         int NS) {
  int t = blockIdx.x;                 // 0..63
  int j = blockIdx.y * 256 + threadIdx.x;  // 0..1023
  float bias = bih[j] + bhh[j];
  float v[32];
#pragma unroll
  for (int b = 0; b < 32; ++b) v[b] = bias;
  for (int s = 0; s < NS; ++s) {
    const float* base = preS + (size_t)s * Mz * G4z;
#pragma unroll
    for (int b = 0; b < 32; ++b)
      v[b] += base[((size_t)b * Tz + t) * G4z + j];
  }
  half8 h[4];
#pragma unroll
  for (int i = 0; i < 32; ++i) ((_Float16*)h)[i] = (_Float16)v[i];
  half8* op = (half8*)(preT + ((size_t)t * G4z + j) * Bz);
#pragma unroll
  for (int i = 0; i < 4; ++i) op[i] = h[i];
}

// ---------------- LSTM: W-stationary in LDS, 8 batch-domains x 4 W-slice WGs ----------------
// WG (d, ws_): owns batches [d*4,d*4+4) x hl slice [ws_*64, ws_*64+64) across 4 gates.
// W slice (256 rows x 256 k fp16, padded) resident in LDS. Per step: exchange h (2 KB)
// via per-step-unique global slots + release/acquire arrival counter (4 producers).
__global__ void __launch_bounds__(256) k_lstm3(const _Float16* __restrict__ Whh16,
                                               const _Float16* __restrict__ preT,
                                               _Float16* __restrict__ hx,   // [8][65][4][256]
                                               int* __restrict__ ctr,       // [8*65]
                                               float* __restrict__ hlast) { // [32][256]
  __shared__ _Float16 Ws[256 * 264];  // 135 KB
  __shared__ _Float16 hs[16 * 264];   // A-frag staging (rows 4..15 stay zero)
  const int tid = threadIdx.x;
  const int d   = blockIdx.x >> 2;    // domain 0..7
  const int ws_ = blockIdx.x & 3;     // W-slice 0..3
  const int wv = tid >> 6;
  const int lane = tid & 63;
  const int quad = lane >> 4, l15 = lane & 15;

  for (int i = tid; i < 16 * 264; i += 256) hs[i] = (_Float16)0.f;
  // Load W slice: local row rp = g*64 + hl64 -> global row g*256 + ws_*64 + hl64
#pragma unroll
  for (int rr = 0; rr < 2; ++rr) {
    int rp = (tid >> 1) + rr * 128;
    int g = rp >> 6, hl64 = rp & 63;
    int grow = g * 256 + ws_ * 64 + hl64;
    const half8* src = (const half8*)(Whh16 + (size_t)grow * HLz + (tid & 1) * 128);
    half8* dst = (half8*)&Ws[rp * 264 + (tid & 1) * 128];
#pragma unroll
    for (int u = 0; u < 16; ++u) dst[u] = src[u];
  }
  float cst[4] = {0.f, 0.f, 0.f, 0.f};
  const int hlG = ws_ * 64 + wv * 16 + l15;  // this lane's hl (valid for quad==0 epilogue)
  __syncthreads();

  for (int t = 0; t < Tz; ++t) {
    // prefetch pre for this step (independent of peers -> issue before the wait)
    half4 pq[4];
    if (quad == 0) {
#pragma unroll
      for (int g = 0; g < 4; ++g)
        pq[g] = *(const half4*)(preT + ((size_t)t * G4z + g * HLz + hlG) * Bz + d * 4);
    }
    if (t > 0) {
      if (tid == 0) {
        while (__hip_atomic_load(&ctr[d * 65 + t], __ATOMIC_ACQUIRE,
                                 __HIP_MEMORY_SCOPE_AGENT) < 4)
          __builtin_amdgcn_s_sleep(2);
      }
      __syncthreads();
      // stage h(t): 4x256 fp16 = 2 KB; one u64 agent-scope load per thread
      const unsigned long long* hsrc =
          (const unsigned long long*)(hx + ((size_t)d * 65 + t) * 1024);
      unsigned long long u =
          __hip_atomic_load(hsrc + tid, __ATOMIC_RELAXED, __HIP_MEMORY_SCOPE_AGENT);
      int m = tid >> 6, k = (tid & 63) * 4;
      *(unsigned long long*)&hs[m * 264 + k] = u;
      __syncthreads();
    }
    floatx4 acc[4] = {};
#pragma unroll
    for (int kt = 0; kt < 8; ++kt) {
      half8 a = *(const half8*)&hs[l15 * 264 + kt * 32 + quad * 8];
#pragma unroll
      for (int g = 0; g < 4; ++g) {
        half8 b = *(const half8*)&Ws[(g * 64 + wv * 16 + l15) * 264 + kt * 32 + quad * 8];
        acc[g] = __builtin_amdgcn_mfma_f32_16x16x32_f16(a, b, acc[g], 0, 0, 0);
      }
    }
    if (quad == 0) {
      unsigned short* hdst =
          (unsigned short*)(hx + ((size_t)d * 65 + t + 1) * 1024);
#pragma unroll
      for (int q = 0; q < 4; ++q) {
        float gi = acc[0][q] + (float)pq[0][q];
        float gf = acc[1][q] + (float)pq[1][q];
        float gg = acc[2][q] + (float)pq[2][q];
        float go = acc[3][q] + (float)pq[3][q];
        float iv = sigm(gi), fv = sigm(gf), gv = tanhh(gg), ov = sigm(go);
        float cn = fv * cst[q] + iv * gv;
        cst[q] = cn;
        float hn = ov * tanhh(cn);
        if (t < Tz - 1) {
          _Float16 hf = (_Float16)hn;
          __hip_atomic_store(&hdst[q * HLz + hlG],
                             __builtin_bit_cast(unsigned short, hf),
                             __ATOMIC_RELAXED, __HIP_MEMORY_SCOPE_AGENT);
        } else {
          hlast[(size_t)(d * 4 + q) * HLz + hlG] = hn;
        }
      }
    }
    if (t < Tz - 1) {
      __syncthreads();   // drains vmem (stores) + LDS reads before flag / restage
      if (tid == 0) {
        __threadfence();
        __hip_atomic_fetch_add(&ctr[d * 65 + t + 1], 1, __ATOMIC_RELEASE,
                               __HIP_MEMORY_SCOPE_AGENT);
      }
    }
  }
}

// out[b,o] = h_last[b,:] @ W_proj[o,:] + b_proj[o]
__global__ void k_proj(const float* __restrict__ hlast, const float* __restrict__ Wp,
                       const float* __restrict__ bp, float* __restrict__ out) {
  int idx = blockIdx.x * 256 + threadIdx.x;
  if (idx >= Bz * OUTz) return;
  int b = idx / OUTz, o = idx % OUTz;
  const float* h = hlast + (size_t)b * HLz;
  const float* wr = Wp + (size_t)o * HLz;
  float s = 0.f;
  for (int k = 0; k < HLz; k += 4) {
    float4 hv = *(const float4*)&h[k];
    float4 wv = *(const float4*)&wr[k];
    s += hv.x * wv.x + hv.y * wv.y + hv.z * wv.z + hv.w * wv.w;
  }
  out[idx] = s + bp[o];
}

extern "C" void kernel_launch(void* const* d_in, const int* in_sizes, int n_in,
                              void* d_out, int out_size, void* d_ws, size_t ws_size,
                              hipStream_t stream) {
  const float* x   = (const float*)d_in[0];
  const int*   ei  = (const int*)d_in[1];
  const float* ew  = (const float*)d_in[2];
  const float* Wg  = (const float*)d_in[3];
  const float* bg  = (const float*)d_in[4];
  const float* Wih = (const float*)d_in[5];
  const float* Whh = (const float*)d_in[6];
  const float* bih = (const float*)d_in[7];
  const float* bhh = (const float*)d_in[8];
  const float* Wp  = (const float*)d_in[9];
  const float* bp  = (const float*)d_in[10];
  float* out = (float*)d_out;
  char* ws = (char*)d_ws;

  int NS = 4;
  while (NS > 1 && OFF_PRES + (size_t)NS * SPLIT_BYTES > ws_size) NS >>= 1;
  if (OFF_PRES + (size_t)NS * SPLIT_BYTES > ws_size) return;

  float* deg   = (float*)(ws + OFF_DEG);
  float* ideg  = (float*)(ws + OFF_IDEG);
  float* norm  = (float*)(ws + OFF_NORM);
  int*   cnt   = (int*)(ws + OFF_CNT);
  int*   roff  = (int*)(ws + OFF_ROFF);
  int*   cur   = (int*)(ws + OFF_CUR);
  int*   csrs  = (int*)(ws + OFF_CSRS);
  float* csrw  = (float*)(ws + OFF_CSRW);
  float* hlast = (float*)(ws + OFF_HLAST);
  _Float16* preT  = (_Float16*)(ws + OFF_PRE16T);
  _Float16* whh16 = (_Float16*)(ws + OFF_WHH16);
  _Float16* hx    = (_Float16*)(ws + OFF_HX);
  int*   ctr2  = (int*)(ws + OFF_CTR2);
  _Float16* seq16 = (_Float16*)(ws + OFF_SEQ);
  _Float16* wih16 = (_Float16*)(ws + OFF_WIH);
  float* preS  = (float*)(ws + OFF_PRES);

  hipMemsetAsync(ws + OFF_CNT, 0, 4096, stream);
  hipMemsetAsync(ws + OFF_CTR2, 0, 4096, stream);

  k_deg_init<<<4, 256, 0, stream>>>(deg);
  k_deg_scatter<<<63, 256, 0, stream>>>(ei, ew, deg);
  k_norm<<<63, 256, 0, stream>>>(ei, ew, deg, norm, ideg);
  k_csr_count<<<63, 256, 0, stream>>>(ei, cnt);
  k_scan<<<1, 1024, 0, stream>>>(cnt, roff, cur);
  k_csr_fill<<<63, 256, 0, stream>>>(ei, norm, cur, csrs, csrw);
  k_f32tof16<<<8000, 256, 0, stream>>>(Wih, wih16, (size_t)G4z * Kz / 8);
  k_f32tof16<<<128, 256, 0, stream>>>(Whh, whh16, (size_t)G4z * HLz / 8);
  k_seq<<<8000, 256, 0, stream>>>(x, Wg, bg, ideg, seq16);
  k_aggseq<<<1000, 256, 0, stream>>>(x, Wg, roff, cnt, csrs, csrw, seq16);
  k_gemm<<<dim3(16, 8, NS), 256, 0, stream>>>(seq16, wih16, preS, Kz / NS, Kz / NS / 32);
  k_reduce<<<dim3(Tz, 4), 256, 0, stream>>>(preS, bih, bhh, preT, NS);
  k_lstm3<<<32, 256, 0, stream>>>(whh16, preT, hx, ctr2, hlast);
  k_proj<<<3, 256, 0, stream>>>(hlast, Wp, bp, out);
}

// Round 5
// 552.052 us; speedup vs baseline: 3.6363x; 1.0973x over previous
//
#include <hip/hip_runtime.h>
#include <stdint.h>

// Problem constants
#define Bz 32
#define Tz 64
#define Nz 1000
#define Cz 8
#define HGz 16
#define HLz 256
#define OUTz 24
#define Ez 16000
#define K2z 8000   // N*C (folded GEMM K)
#define Mz 2048    // B*T
#define G4z 1024   // 4*HL

using half8  = __attribute__((ext_vector_type(8))) _Float16;
using half4  = __attribute__((ext_vector_type(4))) _Float16;
using floatx4 = __attribute__((ext_vector_type(4))) float;

// ---- Workspace layout (bytes) ----
static const size_t OFF_DEG    = 0;         // fp32 [1000]
static const size_t OFF_IDEG   = 4096;      // fp32 [1000]
static const size_t OFF_NORM   = 8192;      // fp32 [16000]
static const size_t OFF_CNT    = 73728;     // int  [1024]
static const size_t OFF_ROFF   = 77824;     // int  [1024]
static const size_t OFF_CUR    = 81920;     // int  [1024]
static const size_t OFF_CSRS   = 86016;     // int  [16000]
static const size_t OFF_CSRW   = 151552;    // fp32 [16000]
static const size_t OFF_HLAST  = 217088;    // fp32 [32][256]
static const size_t OFF_PRE16T = 249856;    // fp16 [64][1024][32]  4,194,304
static const size_t OFF_WHH16  = 4444160;   // fp16 [1024][256]       524,288
static const size_t OFF_HX     = 4968448;   // fp16 [8][65][4][256] 1,064,960
static const size_t OFF_CTR2   = 6033408;   // int  [8*65]              4096
static const size_t OFF_BGC    = 6037504;   // fp32 [1024]              4096
static const size_t OFF_XT     = 6041600;   // fp16 [2048][8000]   32,768,000
static const size_t OFF_WC     = 38809600;  // fp16 [1024][8000]   16,384,000
static const size_t OFF_PRES   = 55193600;  // fp32 [4][2048][1024] 33,554,432
static const size_t WS_NEED    = 88748032;

__device__ __forceinline__ void gl_lds16(const void* g, void* l) {
  __builtin_amdgcn_global_load_lds(
      (__attribute__((address_space(1))) void*)(void*)g,
      (__attribute__((address_space(3))) void*)l, 16, 0, 0);
}

__device__ __forceinline__ float sigm(float x) { return 1.0f / (1.0f + __expf(-x)); }
__device__ __forceinline__ float tanhh(float x) { return 1.0f - 2.0f / (__expf(2.0f * x) + 1.0f); }

// ---------------- GCN prep ----------------
__global__ void k_deg_init(float* deg) {
  int i = blockIdx.x * 256 + threadIdx.x;
  if (i < Nz) deg[i] = 1.0f;
}

__global__ void k_deg_scatter(const int* __restrict__ ei, const float* __restrict__ ew,
                              float* deg) {
  int e = blockIdx.x * 256 + threadIdx.x;
  if (e < Ez) atomicAdd(&deg[ei[Ez + e]], ew[e]);
}

__global__ void k_norm(const int* __restrict__ ei, const float* __restrict__ ew,
                       const float* __restrict__ deg, float* __restrict__ norm,
                       float* __restrict__ ideg) {
  int e = blockIdx.x * 256 + threadIdx.x;
  if (e < Ez) {
    float dr = deg[ei[e]], dc = deg[ei[Ez + e]];
    norm[e] = ew[e] * (1.0f / sqrtf(dr)) * (1.0f / sqrtf(dc));
  }
  if (e < Nz) ideg[e] = 1.0f / deg[e];
}

__global__ void k_csr_count(const int* __restrict__ ei, int* __restrict__ cnt) {
  int e = blockIdx.x * 256 + threadIdx.x;
  if (e < Ez) atomicAdd(&cnt[ei[Ez + e]], 1);
}

__global__ void k_scan(const int* __restrict__ cnt, int* __restrict__ roff,
                       int* __restrict__ cur) {
  __shared__ int s[1024];
  int tid = threadIdx.x;
  int v0 = cnt[tid];
  s[tid] = v0;
  __syncthreads();
  for (int off = 1; off < 1024; off <<= 1) {
    int v = (tid >= off) ? s[tid - off] : 0;
    __syncthreads();
    s[tid] += v;
    __syncthreads();
  }
  int excl = s[tid] - v0;
  roff[tid] = excl;
  cur[tid] = excl;
}

__global__ void k_csr_fill(const int* __restrict__ ei, const float* __restrict__ norm,
                           int* __restrict__ cur, int* __restrict__ csrs,
                           float* __restrict__ csrw) {
  int e = blockIdx.x * 256 + threadIdx.x;
  if (e >= Ez) return;
  int dst = ei[Ez + e];
  int p = atomicAdd(&cur[dst], 1);
  csrs[p] = ei[e];
  csrw[p] = norm[e];
}

// fp32 -> fp16 bulk convert (8 elems/thread)
__global__ void k_f32tof16(const float* __restrict__ src, _Float16* __restrict__ dst,
                           size_t n8) {
  size_t i = (size_t)blockIdx.x * 256 + threadIdx.x;
  if (i >= n8) return;
  float4 a = ((const float4*)src)[i * 2];
  float4 b = ((const float4*)src)[i * 2 + 1];
  half8 h;
  h[0] = (_Float16)a.x; h[1] = (_Float16)a.y; h[2] = (_Float16)a.z; h[3] = (_Float16)a.w;
  h[4] = (_Float16)b.x; h[5] = (_Float16)b.y; h[6] = (_Float16)b.z; h[7] = (_Float16)b.w;
  ((half8*)dst)[i] = h;
}

// Fold W_gcn into W_ih: Wc[j, n*8+c] = sum_h Wih[j, n*16+h] * Wg[c*16+h]
// Also bgc[j] = sum_{n,h} Wih[j, n*16+h] * bg[h].
__global__ void __launch_bounds__(256) k_fold(const float* __restrict__ Wih,
                                              const float* __restrict__ Wg,
                                              const float* __restrict__ bg,
                                              _Float16* __restrict__ wc,
                                              float* __restrict__ bgc) {
  __shared__ float wgs[Cz * HGz];
  __shared__ float bgs[HGz];
  __shared__ float red[256];
  int tid = threadIdx.x;
  int j = blockIdx.x;
  if (tid < Cz * HGz) wgs[tid] = Wg[tid];
  if (tid < HGz) bgs[tid] = bg[tid];
  __syncthreads();
  const float* row = Wih + (size_t)j * (Nz * HGz);
  float bacc = 0.f;
  for (int n = tid; n < Nz; n += 256) {
    const float* p = row + n * HGz;
    float w[16];
    float4 v0 = *(const float4*)p, v1 = *(const float4*)(p + 4);
    float4 v2 = *(const float4*)(p + 8), v3 = *(const float4*)(p + 12);
    w[0]=v0.x; w[1]=v0.y; w[2]=v0.z; w[3]=v0.w;
    w[4]=v1.x; w[5]=v1.y; w[6]=v1.z; w[7]=v1.w;
    w[8]=v2.x; w[9]=v2.y; w[10]=v2.z; w[11]=v2.w;
    w[12]=v3.x; w[13]=v3.y; w[14]=v3.z; w[15]=v3.w;
    half8 o;
#pragma unroll
    for (int c = 0; c < Cz; ++c) {
      float s = 0.f;
#pragma unroll
      for (int h = 0; h < HGz; ++h) s += w[h] * wgs[c * HGz + h];
      o[c] = (_Float16)s;
    }
#pragma unroll
    for (int h = 0; h < HGz; ++h) bacc += w[h] * bgs[h];
    *(half8*)(wc + (size_t)j * K2z + n * Cz) = o;
  }
  red[tid] = bacc;
  __syncthreads();
  for (int off = 128; off > 0; off >>= 1) {
    if (tid < off) red[tid] += red[tid + off];
    __syncthreads();
  }
  if (tid == 0) bgc[j] = red[0];
}

// Batch-0 rows of xt: ideg[n]*x + CSR-gathered neighbor sum (8 channels), fp16.
__global__ void k_xt_agg(const float* __restrict__ x, const float* __restrict__ ideg,
                         const int* __restrict__ roff, const int* __restrict__ cnt,
                         const int* __restrict__ csrs, const float* __restrict__ csrw,
                         _Float16* __restrict__ xt) {
  int g = blockIdx.x * 256 + threadIdx.x;  // t*1000+n
  if (g >= Tz * Nz) return;
  int t = g / Nz, n = g % Nz;
  const float* xp = x + (size_t)g * Cz;
  float4 a = *(const float4*)xp, b = *(const float4*)(xp + 4);
  float id = ideg[n];
  float s[8] = {id*a.x, id*a.y, id*a.z, id*a.w, id*b.x, id*b.y, id*b.z, id*b.w};
  int i0 = roff[n], nc = cnt[n];
  for (int i = i0; i < i0 + nc; ++i) {
    int src = csrs[i];
    float wv = csrw[i];
    const float* q = x + ((size_t)t * Nz + src) * Cz;
    float4 u = *(const float4*)q, v = *(const float4*)(q + 4);
    s[0] += wv * u.x; s[1] += wv * u.y; s[2] += wv * u.z; s[3] += wv * u.w;
    s[4] += wv * v.x; s[5] += wv * v.y; s[6] += wv * v.z; s[7] += wv * v.w;
  }
  half8 h;
#pragma unroll
  for (int c = 0; c < 8; ++c) h[c] = (_Float16)s[c];
  *(half8*)(xt + (size_t)t * K2z + n * Cz) = h;
}

// ---------------- GEMM: preS[z][2048][1024] = xt @ Wc^T (uneven split-K=4) ----------------
__global__ void __launch_bounds__(256) k_gemm(const _Float16* __restrict__ A,
                                              const _Float16* __restrict__ Bm,
                                              float* __restrict__ Cp) {
  __shared__ _Float16 As[128 * 32];
  __shared__ _Float16 Bs[128 * 32];
  const int tid = threadIdx.x;
  const int lane = tid & 63;
  const int wave = tid >> 6;
  const int wm = wave & 1, wn = wave >> 1;
  const int quad = lane >> 4, l15 = lane & 15;
  const size_t tm = (size_t)blockIdx.x * 128;
  const size_t tn = (size_t)blockIdx.y * 128;
  const int k0 = blockIdx.z * 2048;
  const int iters = (blockIdx.z < 3) ? 64 : 58;   // 3*2048 + 1856 = 8000
  float* Cz_ = Cp + (size_t)blockIdx.z * Mz * G4z;
  const int srow = tid >> 2;
  const int skk = (tid & 3) * 8;
  const _Float16* gA0 = A + (tm + srow) * (size_t)K2z + k0 + skk;
  const _Float16* gA1 = gA0 + 64 * (size_t)K2z;
  const _Float16* gB0 = Bm + (tn + srow) * (size_t)K2z + k0 + skk;
  const _Float16* gB1 = gB0 + 64 * (size_t)K2z;
  _Float16* lA0 = &As[tid * 8];
  _Float16* lA1 = &As[2048 + tid * 8];
  _Float16* lB0 = &Bs[tid * 8];
  _Float16* lB1 = &Bs[2048 + tid * 8];
  floatx4 acc[4][4] = {};
  for (int kt = 0; kt < iters; ++kt) {
    __syncthreads();
    gl_lds16(gA0, lA0);
    gl_lds16(gA1, lA1);
    gl_lds16(gB0, lB0);
    gl_lds16(gB1, lB1);
    gA0 += 32; gA1 += 32; gB0 += 32; gB1 += 32;
    __syncthreads();
    half8 af[4], bf[4];
#pragma unroll
    for (int i = 0; i < 4; ++i)
      af[i] = *(const half8*)&As[(wm * 64 + i * 16 + l15) * 32 + quad * 8];
#pragma unroll
    for (int i = 0; i < 4; ++i)
      bf[i] = *(const half8*)&Bs[(wn * 64 + i * 16 + l15) * 32 + quad * 8];
#pragma unroll
    for (int mi = 0; mi < 4; ++mi)
#pragma unroll
      for (int ni = 0; ni < 4; ++ni)
        acc[mi][ni] = __builtin_amdgcn_mfma_f32_16x16x32_f16(af[mi], bf[ni], acc[mi][ni], 0, 0, 0);
  }
#pragma unroll
  for (int mi = 0; mi < 4; ++mi)
#pragma unroll
    for (int ni = 0; ni < 4; ++ni) {
      size_t r0 = tm + wm * 64 + mi * 16 + quad * 4;
      size_t cc = tn + wn * 64 + ni * 16 + l15;
#pragma unroll
      for (int q = 0; q < 4; ++q) Cz_[(r0 + q) * G4z + cc] = acc[mi][ni][q];
    }
}

// ---------------- reduce split-K + biases -> transposed fp16 pre[t][j][batch] ----------------
__global__ void k_reduce(const float* __restrict__ preS, const float* __restrict__ bih,
                         const float* __restrict__ bhh, const float* __restrict__ bgc,
                         _Float16* __restrict__ preT) {
  int t = blockIdx.x;                      // 0..63
  int j = blockIdx.y * 256 + threadIdx.x;  // 0..1023
  float bias = bih[j] + bhh[j] + bgc[j];
  float v[32];
#pragma unroll
  for (int b = 0; b < 32; ++b) v[b] = bias;
  for (int s = 0; s < 4; ++s) {
    const float* base = preS + (size_t)s * Mz * G4z;
#pragma unroll
    for (int b = 0; b < 32; ++b)
      v[b] += base[((size_t)b * Tz + t) * G4z + j];
  }
  half8 h[4];
#pragma unroll
  for (int i = 0; i < 32; ++i) ((_Float16*)h)[i] = (_Float16)v[i];
  half8* op = (half8*)(preT + ((size_t)t * G4z + j) * Bz);
#pragma unroll
  for (int i = 0; i < 4; ++i) op[i] = h[i];
}

// ---------------- LSTM: W-stationary in LDS, 8 batch-domains x 4 W-slice WGs ----------------
__global__ void __launch_bounds__(256) k_lstm3(const _Float16* __restrict__ Whh16,
                                               const _Float16* __restrict__ preT,
                                               _Float16* __restrict__ hx,   // [8][65][4][256]
                                               int* __restrict__ ctr,       // [8*65]
                                               float* __restrict__ hlast) { // [32][256]
  __shared__ _Float16 Ws[256 * 264];  // 135 KB
  __shared__ _Float16 hs[16 * 264];
  const int tid = threadIdx.x;
  const int d   = blockIdx.x >> 2;    // domain 0..7
  const int ws_ = blockIdx.x & 3;     // W-slice 0..3
  const int wv = tid >> 6;
  const int lane = tid & 63;
  const int quad = lane >> 4, l15 = lane & 15;

  for (int i = tid; i < 16 * 264; i += 256) hs[i] = (_Float16)0.f;
#pragma unroll
  for (int rr = 0; rr < 2; ++rr) {
    int rp = (tid >> 1) + rr * 128;
    int g = rp >> 6, hl64 = rp & 63;
    int grow = g * 256 + ws_ * 64 + hl64;
    const half8* src = (const half8*)(Whh16 + (size_t)grow * HLz + (tid & 1) * 128);
    half8* dst = (half8*)&Ws[rp * 264 + (tid & 1) * 128];
#pragma unroll
    for (int u = 0; u < 16; ++u) dst[u] = src[u];
  }
  float cst[4] = {0.f, 0.f, 0.f, 0.f};
  const int hlG = ws_ * 64 + wv * 16 + l15;
  __syncthreads();

  for (int t = 0; t < Tz; ++t) {
    half4 pq[4];
    if (quad == 0) {
#pragma unroll
      for (int g = 0; g < 4; ++g)
        pq[g] = *(const half4*)(preT + ((size_t)t * G4z + g * HLz + hlG) * Bz + d * 4);
    }
    if (t > 0) {
      // all threads poll relaxed (wave-coalesced), single acquire fence after
      while (__hip_atomic_load(&ctr[d * 65 + t], __ATOMIC_RELAXED,
                               __HIP_MEMORY_SCOPE_AGENT) < 4)
        __builtin_amdgcn_s_sleep(1);
      __builtin_amdgcn_fence(__ATOMIC_ACQUIRE, "agent");
      const unsigned long long* hsrc =
          (const unsigned long long*)(hx + ((size_t)d * 65 + t) * 1024);
      unsigned long long u =
          __hip_atomic_load(hsrc + tid, __ATOMIC_RELAXED, __HIP_MEMORY_SCOPE_AGENT);
      int m = tid >> 6, k = (tid & 63) * 4;
      *(unsigned long long*)&hs[m * 264 + k] = u;
      __syncthreads();
    }
    floatx4 acc[4] = {};
#pragma unroll
    for (int kt = 0; kt < 8; ++kt) {
      half8 a = *(const half8*)&hs[l15 * 264 + kt * 32 + quad * 8];
#pragma unroll
      for (int g = 0; g < 4; ++g) {
        half8 b = *(const half8*)&Ws[(g * 64 + wv * 16 + l15) * 264 + kt * 32 + quad * 8];
        acc[g] = __builtin_amdgcn_mfma_f32_16x16x32_f16(a, b, acc[g], 0, 0, 0);
      }
    }
    if (quad == 0) {
      unsigned short* hdst =
          (unsigned short*)(hx + ((size_t)d * 65 + t + 1) * 1024);
#pragma unroll
      for (int q = 0; q < 4; ++q) {
        float gi = acc[0][q] + (float)pq[0][q];
        float gf = acc[1][q] + (float)pq[1][q];
        float gg = acc[2][q] + (float)pq[2][q];
        float go = acc[3][q] + (float)pq[3][q];
        float iv = sigm(gi), fv = sigm(gf), gv = tanhh(gg), ov = sigm(go);
        float cn = fv * cst[q] + iv * gv;
        cst[q] = cn;
        float hn = ov * tanhh(cn);
        if (t < Tz - 1) {
          _Float16 hf = (_Float16)hn;
          __hip_atomic_store(&hdst[q * HLz + hlG],
                             __builtin_bit_cast(unsigned short, hf),
                             __ATOMIC_RELAXED, __HIP_MEMORY_SCOPE_AGENT);
        } else {
          hlast[(size_t)(d * 4 + q) * HLz + hlG] = hn;
        }
      }
    }
    if (t < Tz - 1) {
      __syncthreads();  // drains each wave's vmcnt -> h stores at coherence point
      if (tid == 0) {
        __hip_atomic_fetch_add(&ctr[d * 65 + t + 1], 1, __ATOMIC_RELEASE,
                               __HIP_MEMORY_SCOPE_AGENT);
      }
    }
  }
}

// out[b,o] = h_last[b,:] @ W_proj[o,:] + b_proj[o]
__global__ void k_proj(const float* __restrict__ hlast, const float* __restrict__ Wp,
                       const float* __restrict__ bp, float* __restrict__ out) {
  int idx = blockIdx.x * 256 + threadIdx.x;
  if (idx >= Bz * OUTz) return;
  int b = idx / OUTz, o = idx % OUTz;
  const float* h = hlast + (size_t)b * HLz;
  const float* wr = Wp + (size_t)o * HLz;
  float s = 0.f;
  for (int k = 0; k < HLz; k += 4) {
    float4 hv = *(const float4*)&h[k];
    float4 wv = *(const float4*)&wr[k];
    s += hv.x * wv.x + hv.y * wv.y + hv.z * wv.z + hv.w * wv.w;
  }
  out[idx] = s + bp[o];
}

extern "C" void kernel_launch(void* const* d_in, const int* in_sizes, int n_in,
                              void* d_out, int out_size, void* d_ws, size_t ws_size,
                              hipStream_t stream) {
  const float* x   = (const float*)d_in[0];
  const int*   ei  = (const int*)d_in[1];
  const float* ew  = (const float*)d_in[2];
  const float* Wg  = (const float*)d_in[3];
  const float* bg  = (const float*)d_in[4];
  const float* Wih = (const float*)d_in[5];
  const float* Whh = (const float*)d_in[6];
  const float* bih = (const float*)d_in[7];
  const float* bhh = (const float*)d_in[8];
  const float* Wp  = (const float*)d_in[9];
  const float* bp  = (const float*)d_in[10];
  float* out = (float*)d_out;
  char* ws = (char*)d_ws;
  if (ws_size < WS_NEED) return;

  float* deg   = (float*)(ws + OFF_DEG);
  float* ideg  = (float*)(ws + OFF_IDEG);
  float* norm  = (float*)(ws + OFF_NORM);
  int*   cnt   = (int*)(ws + OFF_CNT);
  int*   roff  = (int*)(ws + OFF_ROFF);
  int*   cur   = (int*)(ws + OFF_CUR);
  int*   csrs  = (int*)(ws + OFF_CSRS);
  float* csrw  = (float*)(ws + OFF_CSRW);
  float* hlast = (float*)(ws + OFF_HLAST);
  _Float16* preT  = (_Float16*)(ws + OFF_PRE16T);
  _Float16* whh16 = (_Float16*)(ws + OFF_WHH16);
  _Float16* hx    = (_Float16*)(ws + OFF_HX);
  int*   ctr2  = (int*)(ws + OFF_CTR2);
  float* bgc   = (float*)(ws + OFF_BGC);
  _Float16* xt    = (_Float16*)(ws + OFF_XT);
  _Float16* wc    = (_Float16*)(ws + OFF_WC);
  float* preS  = (float*)(ws + OFF_PRES);

  hipMemsetAsync(ws + OFF_CNT, 0, 4096, stream);
  hipMemsetAsync(ws + OFF_CTR2, 0, 4096, stream);

  k_deg_init<<<4, 256, 0, stream>>>(deg);
  k_deg_scatter<<<63, 256, 0, stream>>>(ei, ew, deg);
  k_norm<<<63, 256, 0, stream>>>(ei, ew, deg, norm, ideg);
  k_csr_count<<<63, 256, 0, stream>>>(ei, cnt);
  k_scan<<<1, 1024, 0, stream>>>(cnt, roff, cur);
  k_csr_fill<<<63, 256, 0, stream>>>(ei, norm, cur, csrs, csrw);
  k_fold<<<1024, 256, 0, stream>>>(Wih, Wg, bg, wc, bgc);
  k_f32tof16<<<128, 256, 0, stream>>>(Whh, whh16, (size_t)G4z * HLz / 8);
  // batches 1..31: straight fp16 cast of x (region starts at bt=64)
  k_f32tof16<<<7750, 256, 0, stream>>>(x + (size_t)Tz * K2z, xt + (size_t)Tz * K2z,
                                       (size_t)(Mz - Tz) * K2z / 8);
  k_xt_agg<<<250, 256, 0, stream>>>(x, ideg, roff, cnt, csrs, csrw, xt);
  k_gemm<<<dim3(16, 8, 4), 256, 0, stream>>>(xt, wc, preS);
  k_reduce<<<dim3(Tz, 4), 256, 0, stream>>>(preS, bih, bhh, bgc, preT);
  k_lstm3<<<32, 256, 0, stream>>>(whh16, preT, hx, ctr2, hlast);
  k_proj<<<3, 256, 0, stream>>>(hlast, Wp, bp, out);
}

// Round 6
// 459.891 us; speedup vs baseline: 4.3650x; 1.2004x over previous
//
#include <hip/hip_runtime.h>
#include <stdint.h>

// Problem constants
#define Bz 32
#define Tz 64
#define Nz 1000
#define Cz 8
#define HGz 16
#define HLz 256
#define OUTz 24
#define Ez 16000
#define K2z 8000   // N*C (folded GEMM K)
#define Mz 2048    // B*T
#define G4z 1024   // 4*HL

using half8  = __attribute__((ext_vector_type(8))) _Float16;
using half4  = __attribute__((ext_vector_type(4))) _Float16;
using floatx4 = __attribute__((ext_vector_type(4))) float;

#define SENT 0x7E7E7E7E7E7E7E7EULL  // 4x fp16 NaN, memset-able byte 0x7E

// ---- Workspace layout (bytes) ----
static const size_t OFF_IDEG   = 4096;      // fp32 [1000]
static const size_t OFF_CNT    = 73728;     // int  [1024]
static const size_t OFF_ROFF   = 77824;     // int  [1024]
static const size_t OFF_CSRS   = 86016;     // int  [16000]
static const size_t OFF_CSRW   = 151552;    // fp32 [16000]
static const size_t OFF_HLAST  = 217088;    // fp32 [32][256]
static const size_t OFF_PRE16T = 249856;    // fp16 [64][1024][32]  4,194,304
static const size_t OFF_WHH16  = 4444160;   // fp16 [1024][256]       524,288
static const size_t OFF_HX     = 4968448;   // u64  [8][65][256]    1,064,960
static const size_t OFF_BGC    = 6037504;   // fp32 [1024]
static const size_t OFF_XT     = 6041600;   // fp16 [2048][8000]   32,768,000
static const size_t OFF_WC     = 38809600;  // fp16 [1024][8000]   16,384,000
static const size_t OFF_PRES   = 55193600;  // fp32 [4][2048][1024] 33,554,432
static const size_t WS_NEED    = 88748032;

__device__ __forceinline__ void gl_lds16(const void* g, void* l) {
  __builtin_amdgcn_global_load_lds(
      (__attribute__((address_space(1))) void*)(void*)g,
      (__attribute__((address_space(3))) void*)l, 16, 0, 0);
}

__device__ __forceinline__ float sigm(float x) { return 1.0f / (1.0f + __expf(-x)); }
__device__ __forceinline__ float tanhh(float x) { return 1.0f - 2.0f / (__expf(2.0f * x) + 1.0f); }

// ---------------- fused GCN prep: deg, norm, CSR (one WG, LDS atomics + LDS scan) ----------------
__global__ void __launch_bounds__(1024) k_prep(const int* __restrict__ ei,
                                               const float* __restrict__ ew,
                                               float* __restrict__ ideg,
                                               int* __restrict__ cntg,
                                               int* __restrict__ roffg,
                                               int* __restrict__ csrs,
                                               float* __restrict__ csrw) {
  __shared__ float disS[1024];   // deg, then 1/sqrt(deg)
  __shared__ int   cntS[1024];
  __shared__ int   curS[1024];
  __shared__ int   scanS[1024];
  int tid = threadIdx.x;
  disS[tid] = 1.0f;
  cntS[tid] = 0;
  __syncthreads();
  for (int e = tid; e < Ez; e += 1024) {
    int col = ei[Ez + e];
    atomicAdd(&disS[col], ew[e]);
    atomicAdd(&cntS[col], 1);
  }
  __syncthreads();
  float d = disS[tid];
  float dis = 1.0f / sqrtf(d);
  if (tid < Nz) ideg[tid] = 1.0f / d;
  __syncthreads();
  disS[tid] = dis;
  // exclusive scan of cnt
  int v0 = cntS[tid];
  scanS[tid] = v0;
  __syncthreads();
  for (int off = 1; off < 1024; off <<= 1) {
    int v = (tid >= off) ? scanS[tid - off] : 0;
    __syncthreads();
    scanS[tid] += v;
    __syncthreads();
  }
  int excl = scanS[tid] - v0;
  roffg[tid] = excl;
  cntg[tid] = v0;
  curS[tid] = excl;
  __syncthreads();
  for (int e = tid; e < Ez; e += 1024) {
    int row = ei[e], col = ei[Ez + e];
    int p = atomicAdd(&curS[col], 1);
    csrs[p] = row;
    csrw[p] = disS[row] * ew[e] * disS[col];
  }
}

// Fold W_gcn into W_ih (blocks 0..1023); blocks 1024..1151 cast Whh -> fp16.
__global__ void __launch_bounds__(256) k_fold(const float* __restrict__ Wih,
                                              const float* __restrict__ Wg,
                                              const float* __restrict__ bg,
                                              _Float16* __restrict__ wc,
                                              float* __restrict__ bgc,
                                              const float* __restrict__ Whh,
                                              _Float16* __restrict__ whh16) {
  __shared__ float wgs[Cz * HGz];
  __shared__ float bgs[HGz];
  __shared__ float red[256];
  int tid = threadIdx.x;
  int j = blockIdx.x;
  if (j >= 1024) {
    size_t i = (size_t)(j - 1024) * 256 + tid;  // 32768 half8s
    float4 a = ((const float4*)Whh)[i * 2];
    float4 b = ((const float4*)Whh)[i * 2 + 1];
    half8 h;
    h[0] = (_Float16)a.x; h[1] = (_Float16)a.y; h[2] = (_Float16)a.z; h[3] = (_Float16)a.w;
    h[4] = (_Float16)b.x; h[5] = (_Float16)b.y; h[6] = (_Float16)b.z; h[7] = (_Float16)b.w;
    ((half8*)whh16)[i] = h;
    return;
  }
  if (tid < Cz * HGz) wgs[tid] = Wg[tid];
  if (tid < HGz) bgs[tid] = bg[tid];
  __syncthreads();
  const float* row = Wih + (size_t)j * (Nz * HGz);
  float bacc = 0.f;
  for (int n = tid; n < Nz; n += 256) {
    const float* p = row + n * HGz;
    float w[16];
    float4 v0 = *(const float4*)p, v1 = *(const float4*)(p + 4);
    float4 v2 = *(const float4*)(p + 8), v3 = *(const float4*)(p + 12);
    w[0]=v0.x; w[1]=v0.y; w[2]=v0.z; w[3]=v0.w;
    w[4]=v1.x; w[5]=v1.y; w[6]=v1.z; w[7]=v1.w;
    w[8]=v2.x; w[9]=v2.y; w[10]=v2.z; w[11]=v2.w;
    w[12]=v3.x; w[13]=v3.y; w[14]=v3.z; w[15]=v3.w;
    half8 o;
#pragma unroll
    for (int c = 0; c < Cz; ++c) {
      float s = 0.f;
#pragma unroll
      for (int h = 0; h < HGz; ++h) s += w[h] * wgs[c * HGz + h];
      o[c] = (_Float16)s;
    }
#pragma unroll
    for (int h = 0; h < HGz; ++h) bacc += w[h] * bgs[h];
    *(half8*)(wc + (size_t)j * K2z + n * Cz) = o;
  }
  red[tid] = bacc;
  __syncthreads();
  for (int off = 128; off > 0; off >>= 1) {
    if (tid < off) red[tid] += red[tid + off];
    __syncthreads();
  }
  if (tid == 0) bgc[j] = red[0];
}

// xt: blocks 0..249 = batch-0 rows (ideg*x + CSR neighbor agg); blocks 250..7999 = fp16 cast of x batches 1..31.
__global__ void k_xt(const float* __restrict__ x, const float* __restrict__ ideg,
                     const int* __restrict__ roff, const int* __restrict__ cnt,
                     const int* __restrict__ csrs, const float* __restrict__ csrw,
                     _Float16* __restrict__ xt) {
  if (blockIdx.x >= 250) {
    size_t i = (size_t)(blockIdx.x - 250) * 256 + threadIdx.x;
    const float* src = x + (size_t)Tz * K2z;
    _Float16* dst = xt + (size_t)Tz * K2z;
    float4 a = ((const float4*)src)[i * 2];
    float4 b = ((const float4*)src)[i * 2 + 1];
    half8 h;
    h[0] = (_Float16)a.x; h[1] = (_Float16)a.y; h[2] = (_Float16)a.z; h[3] = (_Float16)a.w;
    h[4] = (_Float16)b.x; h[5] = (_Float16)b.y; h[6] = (_Float16)b.z; h[7] = (_Float16)b.w;
    ((half8*)dst)[i] = h;
    return;
  }
  int g = blockIdx.x * 256 + threadIdx.x;  // t*1000+n
  if (g >= Tz * Nz) return;
  int t = g / Nz, n = g % Nz;
  const float* xp = x + (size_t)g * Cz;
  float4 a = *(const float4*)xp, b = *(const float4*)(xp + 4);
  float id = ideg[n];
  float s[8] = {id*a.x, id*a.y, id*a.z, id*a.w, id*b.x, id*b.y, id*b.z, id*b.w};
  int i0 = roff[n], nc = cnt[n];
  for (int i = i0; i < i0 + nc; ++i) {
    int src = csrs[i];
    float wv = csrw[i];
    const float* q = x + ((size_t)t * Nz + src) * Cz;
    float4 u = *(const float4*)q, v = *(const float4*)(q + 4);
    s[0] += wv * u.x; s[1] += wv * u.y; s[2] += wv * u.z; s[3] += wv * u.w;
    s[4] += wv * v.x; s[5] += wv * v.y; s[6] += wv * v.z; s[7] += wv * v.w;
  }
  half8 h;
#pragma unroll
  for (int c = 0; c < 8; ++c) h[c] = (_Float16)s[c];
  *(half8*)(xt + (size_t)t * K2z + n * Cz) = h;
}

// ---------------- GEMM: preS[z][2048][1024] = xt @ Wc^T (uneven split-K=4) ----------------
__global__ void __launch_bounds__(256) k_gemm(const _Float16* __restrict__ A,
                                              const _Float16* __restrict__ Bm,
                                              float* __restrict__ Cp) {
  __shared__ _Float16 As[128 * 32];
  __shared__ _Float16 Bs[128 * 32];
  const int tid = threadIdx.x;
  const int lane = tid & 63;
  const int wave = tid >> 6;
  const int wm = wave & 1, wn = wave >> 1;
  const int quad = lane >> 4, l15 = lane & 15;
  const size_t tm = (size_t)blockIdx.x * 128;
  const size_t tn = (size_t)blockIdx.y * 128;
  const int k0 = blockIdx.z * 2048;
  const int iters = (blockIdx.z < 3) ? 64 : 58;   // 3*2048 + 1856 = 8000
  float* Cz_ = Cp + (size_t)blockIdx.z * Mz * G4z;
  const int srow = tid >> 2;
  const int skk = (tid & 3) * 8;
  const _Float16* gA0 = A + (tm + srow) * (size_t)K2z + k0 + skk;
  const _Float16* gA1 = gA0 + 64 * (size_t)K2z;
  const _Float16* gB0 = Bm + (tn + srow) * (size_t)K2z + k0 + skk;
  const _Float16* gB1 = gB0 + 64 * (size_t)K2z;
  _Float16* lA0 = &As[tid * 8];
  _Float16* lA1 = &As[2048 + tid * 8];
  _Float16* lB0 = &Bs[tid * 8];
  _Float16* lB1 = &Bs[2048 + tid * 8];
  floatx4 acc[4][4] = {};
  for (int kt = 0; kt < iters; ++kt) {
    __syncthreads();
    gl_lds16(gA0, lA0);
    gl_lds16(gA1, lA1);
    gl_lds16(gB0, lB0);
    gl_lds16(gB1, lB1);
    gA0 += 32; gA1 += 32; gB0 += 32; gB1 += 32;
    __syncthreads();
    half8 af[4], bf[4];
#pragma unroll
    for (int i = 0; i < 4; ++i)
      af[i] = *(const half8*)&As[(wm * 64 + i * 16 + l15) * 32 + quad * 8];
#pragma unroll
    for (int i = 0; i < 4; ++i)
      bf[i] = *(const half8*)&Bs[(wn * 64 + i * 16 + l15) * 32 + quad * 8];
#pragma unroll
    for (int mi = 0; mi < 4; ++mi)
#pragma unroll
      for (int ni = 0; ni < 4; ++ni)
        acc[mi][ni] = __builtin_amdgcn_mfma_f32_16x16x32_f16(af[mi], bf[ni], acc[mi][ni], 0, 0, 0);
  }
#pragma unroll
  for (int mi = 0; mi < 4; ++mi)
#pragma unroll
    for (int ni = 0; ni < 4; ++ni) {
      size_t r0 = tm + wm * 64 + mi * 16 + quad * 4;
      size_t cc = tn + wn * 64 + ni * 16 + l15;
#pragma unroll
      for (int q = 0; q < 4; ++q) Cz_[(r0 + q) * G4z + cc] = acc[mi][ni][q];
    }
}

// ---------------- reduce split-K + biases -> transposed fp16 pre[t][j][batch] ----------------
__global__ void k_reduce(const float* __restrict__ preS, const float* __restrict__ bih,
                         const float* __restrict__ bhh, const float* __restrict__ bgc,
                         _Float16* __restrict__ preT) {
  int t = blockIdx.x;                      // 0..63
  int j = blockIdx.y * 256 + threadIdx.x;  // 0..1023
  float bias = bih[j] + bhh[j] + bgc[j];
  float v[32];
#pragma unroll
  for (int b = 0; b < 32; ++b) v[b] = bias;
  for (int s = 0; s < 4; ++s) {
    const float* base = preS + (size_t)s * Mz * G4z;
#pragma unroll
    for (int b = 0; b < 32; ++b)
      v[b] += base[((size_t)b * Tz + t) * G4z + j];
  }
  half8 h[4];
#pragma unroll
  for (int i = 0; i < 32; ++i) ((_Float16*)h)[i] = (_Float16)v[i];
  half8* op = (half8*)(preT + ((size_t)t * G4z + j) * Bz);
#pragma unroll
  for (int i = 0; i < 4; ++i) op[i] = h[i];
}

// ---------------- LSTM: W-stationary LDS; h-exchange = NaN-sentinel data polling (no flags) ----------------
// hx layout: u64 [d][t][hl]  (one u64 = 4 batches' fp16 h at this hl). Producers store relaxed
// agent u64; consumers poll their own u64 until != SENT. Per-location atomicity makes the data
// its own ready flag -- removes the flag round-trip of R4/R5.
__global__ void __launch_bounds__(256) k_lstm4(const _Float16* __restrict__ Whh16,
                                               const _Float16* __restrict__ preT,
                                               unsigned long long* __restrict__ hx, // [8][65][256]
                                               float* __restrict__ hlast) {         // [32][256]
  __shared__ _Float16 Ws[256 * 264];     // 135 KB, W slice resident
  __shared__ _Float16 hs[2][16 * 264];   // parity-double-buffered h staging
  const int tid = threadIdx.x;
  const int d   = blockIdx.x >> 2;    // domain 0..7 (4 batches each)
  const int ws_ = blockIdx.x & 3;     // W-slice 0..3 (64 hl each)
  const int wv = tid >> 6;
  const int lane = tid & 63;
  const int quad = lane >> 4, l15 = lane & 15;

  for (int i = tid; i < 2 * 16 * 264; i += 256) ((_Float16*)hs)[i] = (_Float16)0.f;
#pragma unroll
  for (int rr = 0; rr < 2; ++rr) {
    int rp = (tid >> 1) + rr * 128;
    int g = rp >> 6, hl64 = rp & 63;
    int grow = g * 256 + ws_ * 64 + hl64;
    const half8* src = (const half8*)(Whh16 + (size_t)grow * HLz + (tid & 1) * 128);
    half8* dst = (half8*)&Ws[rp * 264 + (tid & 1) * 128];
#pragma unroll
    for (int u = 0; u < 16; ++u) dst[u] = src[u];
  }
  float cst[4] = {0.f, 0.f, 0.f, 0.f};
  const int hlG = ws_ * 64 + wv * 16 + l15;
  __syncthreads();

  for (int t = 0; t < Tz; ++t) {
    // prefetch pre for this step (independent of peers)
    half4 pq[4];
    if (quad == 0) {
#pragma unroll
      for (int g = 0; g < 4; ++g)
        pq[g] = *(const half4*)(preT + ((size_t)t * G4z + g * HLz + hlG) * Bz + d * 4);
    }
    if (t > 0) {
      const unsigned long long* hsrc = hx + ((size_t)d * 65 + t) * 256;
      unsigned long long u;
      while ((u = __hip_atomic_load(hsrc + tid, __ATOMIC_RELAXED,
                                    __HIP_MEMORY_SCOPE_AGENT)) == SENT)
        __builtin_amdgcn_s_sleep(1);
      half4 hv = __builtin_bit_cast(half4, u);
      _Float16* hb = &hs[t & 1][0];
#pragma unroll
      for (int q = 0; q < 4; ++q) hb[q * 264 + tid] = hv[q];
    }
    __syncthreads();   // hs ready; also orders prior-step LDS reads vs this-step writes
    floatx4 acc[4] = {};
    const _Float16* hrow = &hs[t & 1][0];
#pragma unroll
    for (int kt = 0; kt < 8; ++kt) {
      half8 a = *(const half8*)&hrow[l15 * 264 + kt * 32 + quad * 8];
#pragma unroll
      for (int g = 0; g < 4; ++g) {
        half8 b = *(const half8*)&Ws[(g * 64 + wv * 16 + l15) * 264 + kt * 32 + quad * 8];
        acc[g] = __builtin_amdgcn_mfma_f32_16x16x32_f16(a, b, acc[g], 0, 0, 0);
      }
    }
    if (quad == 0) {
      half4 o;
#pragma unroll
      for (int q = 0; q < 4; ++q) {
        float gi = acc[0][q] + (float)pq[0][q];
        float gf = acc[1][q] + (float)pq[1][q];
        float gg = acc[2][q] + (float)pq[2][q];
        float go = acc[3][q] + (float)pq[3][q];
        float iv = sigm(gi), fv = sigm(gf), gv = tanhh(gg), ov = sigm(go);
        float cn = fv * cst[q] + iv * gv;
        cst[q] = cn;
        float hn = ov * tanhh(cn);
        o[q] = (_Float16)hn;
        if (t == Tz - 1) hlast[(size_t)(d * 4 + q) * HLz + hlG] = hn;
      }
      if (t < Tz - 1) {
        __hip_atomic_store(hx + ((size_t)d * 65 + t + 1) * 256 + hlG,
                           __builtin_bit_cast(unsigned long long, o),
                           __ATOMIC_RELAXED, __HIP_MEMORY_SCOPE_AGENT);
      }
    }
  }
}

// out[b,o] = h_last[b,:] @ W_proj[o,:] + b_proj[o]
__global__ void k_proj(const float* __restrict__ hlast, const float* __restrict__ Wp,
                       const float* __restrict__ bp, float* __restrict__ out) {
  int idx = blockIdx.x * 256 + threadIdx.x;
  if (idx >= Bz * OUTz) return;
  int b = idx / OUTz, o = idx % OUTz;
  const float* h = hlast + (size_t)b * HLz;
  const float* wr = Wp + (size_t)o * HLz;
  float s = 0.f;
  for (int k = 0; k < HLz; k += 4) {
    float4 hv = *(const float4*)&h[k];
    float4 wv = *(const float4*)&wr[k];
    s += hv.x * wv.x + hv.y * wv.y + hv.z * wv.z + hv.w * wv.w;
  }
  out[idx] = s + bp[o];
}

extern "C" void kernel_launch(void* const* d_in, const int* in_sizes, int n_in,
                              void* d_out, int out_size, void* d_ws, size_t ws_size,
                              hipStream_t stream) {
  const float* x   = (const float*)d_in[0];
  const int*   ei  = (const int*)d_in[1];
  const float* ew  = (const float*)d_in[2];
  const float* Wg  = (const float*)d_in[3];
  const float* bg  = (const float*)d_in[4];
  const float* Wih = (const float*)d_in[5];
  const float* Whh = (const float*)d_in[6];
  const float* bih = (const float*)d_in[7];
  const float* bhh = (const float*)d_in[8];
  const float* Wp  = (const float*)d_in[9];
  const float* bp  = (const float*)d_in[10];
  float* out = (float*)d_out;
  char* ws = (char*)d_ws;
  if (ws_size < WS_NEED) return;

  float* ideg  = (float*)(ws + OFF_IDEG);
  int*   cnt   = (int*)(ws + OFF_CNT);
  int*   roff  = (int*)(ws + OFF_ROFF);
  int*   csrs  = (int*)(ws + OFF_CSRS);
  float* csrw  = (float*)(ws + OFF_CSRW);
  float* hlast = (float*)(ws + OFF_HLAST);
  _Float16* preT  = (_Float16*)(ws + OFF_PRE16T);
  _Float16* whh16 = (_Float16*)(ws + OFF_WHH16);
  unsigned long long* hx = (unsigned long long*)(ws + OFF_HX);
  float* bgc   = (float*)(ws + OFF_BGC);
  _Float16* xt    = (_Float16*)(ws + OFF_XT);
  _Float16* wc    = (_Float16*)(ws + OFF_WC);
  float* preS  = (float*)(ws + OFF_PRES);

  // hx = NaN sentinel (byte-uniform); slot t=0 is never read (h0=0 handled in-kernel)
  hipMemsetAsync(ws + OFF_HX, 0x7E, (size_t)8 * 65 * 256 * 8, stream);

  k_prep<<<1, 1024, 0, stream>>>(ei, ew, ideg, cnt, roff, csrs, csrw);
  k_fold<<<1152, 256, 0, stream>>>(Wih, Wg, bg, wc, bgc, Whh, whh16);
  k_xt<<<8000, 256, 0, stream>>>(x, ideg, roff, cnt, csrs, csrw, xt);
  k_gemm<<<dim3(16, 8, 4), 256, 0, stream>>>(xt, wc, preS);
  k_reduce<<<dim3(Tz, 4), 256, 0, stream>>>(preS, bih, bhh, bgc, preT);
  k_lstm4<<<32, 256, 0, stream>>>(whh16, preT, hx, hlast);
  k_proj<<<3, 256, 0, stream>>>(hlast, Wp, bp, out);
}

// Round 7
// 455.137 us; speedup vs baseline: 4.4106x; 1.0104x over previous
//
#include <hip/hip_runtime.h>
#include <stdint.h>

// Problem constants
#define Bz 32
#define Tz 64
#define Nz 1000
#define Cz 8
#define HGz 16
#define HLz 256
#define OUTz 24
#define Ez 16000
#define K2z 8000   // N*C (folded GEMM K)
#define Mz 2048    // B*T
#define G4z 1024   // 4*HL
#define NSz 8      // split-K count

using half8  = __attribute__((ext_vector_type(8))) _Float16;
using half4  = __attribute__((ext_vector_type(4))) _Float16;
using floatx4 = __attribute__((ext_vector_type(4))) float;

#define SENT 0x7E7E7E7E7E7E7E7EULL  // 4x fp16 NaN, memset-able byte 0x7E

// ---- Workspace layout (bytes) ----
static const size_t OFF_IDEG   = 4096;      // fp32 [1000]
static const size_t OFF_CNT    = 73728;     // int  [1024]
static const size_t OFF_ROFF   = 77824;     // int  [1024]
static const size_t OFF_CSRS   = 86016;     // int  [16000]
static const size_t OFF_CSRW   = 151552;    // fp32 [16000]
static const size_t OFF_HLAST  = 217088;    // fp32 [32][256]
static const size_t OFF_PRE16T = 249856;    // fp16 [64][1024][32]  4,194,304
static const size_t OFF_WHH16  = 4444160;   // fp16 [1024][256]       524,288
static const size_t OFF_HX     = 4968448;   // u64  [8][65][256]    1,064,960
static const size_t OFF_BGC    = 6037504;   // fp32 [1024]
static const size_t OFF_XT     = 6041600;   // fp16 [2048][8000]   32,768,000
static const size_t OFF_WC     = 38809600;  // fp16 [1024][8000]   16,384,000
static const size_t OFF_PRES   = 55193600;  // fp16 [8][2048][1024] 33,554,432
static const size_t WS_NEED    = 88748032;

__device__ __forceinline__ void gl_lds16(const void* g, void* l) {
  __builtin_amdgcn_global_load_lds(
      (__attribute__((address_space(1))) void*)(void*)g,
      (__attribute__((address_space(3))) void*)l, 16, 0, 0);
}

__device__ __forceinline__ float sigm(float x) { return 1.0f / (1.0f + __expf(-x)); }
__device__ __forceinline__ float tanhh(float x) { return 1.0f - 2.0f / (__expf(2.0f * x) + 1.0f); }

// ---------------- fused GCN prep: deg, norm, CSR (one WG, LDS atomics + LDS scan) ----------------
__global__ void __launch_bounds__(1024) k_prep(const int* __restrict__ ei,
                                               const float* __restrict__ ew,
                                               float* __restrict__ ideg,
                                               int* __restrict__ cntg,
                                               int* __restrict__ roffg,
                                               int* __restrict__ csrs,
                                               float* __restrict__ csrw) {
  __shared__ float disS[1024];   // deg, then 1/sqrt(deg)
  __shared__ int   cntS[1024];
  __shared__ int   curS[1024];
  __shared__ int   scanS[1024];
  int tid = threadIdx.x;
  disS[tid] = 1.0f;
  cntS[tid] = 0;
  __syncthreads();
  for (int e = tid; e < Ez; e += 1024) {
    int col = ei[Ez + e];
    atomicAdd(&disS[col], ew[e]);
    atomicAdd(&cntS[col], 1);
  }
  __syncthreads();
  float d = disS[tid];
  float dis = 1.0f / sqrtf(d);
  if (tid < Nz) ideg[tid] = 1.0f / d;
  __syncthreads();
  disS[tid] = dis;
  // exclusive scan of cnt
  int v0 = cntS[tid];
  scanS[tid] = v0;
  __syncthreads();
  for (int off = 1; off < 1024; off <<= 1) {
    int v = (tid >= off) ? scanS[tid - off] : 0;
    __syncthreads();
    scanS[tid] += v;
    __syncthreads();
  }
  int excl = scanS[tid] - v0;
  roffg[tid] = excl;
  cntg[tid] = v0;
  curS[tid] = excl;
  __syncthreads();
  for (int e = tid; e < Ez; e += 1024) {
    int row = ei[e], col = ei[Ez + e];
    int p = atomicAdd(&curS[col], 1);
    csrs[p] = row;
    csrw[p] = disS[row] * ew[e] * disS[col];
  }
}

// Fold W_gcn into W_ih (blocks 0..1023); blocks 1024..1151 cast Whh -> fp16.
__global__ void __launch_bounds__(256) k_fold(const float* __restrict__ Wih,
                                              const float* __restrict__ Wg,
                                              const float* __restrict__ bg,
                                              _Float16* __restrict__ wc,
                                              float* __restrict__ bgc,
                                              const float* __restrict__ Whh,
                                              _Float16* __restrict__ whh16) {
  __shared__ float wgs[Cz * HGz];
  __shared__ float bgs[HGz];
  __shared__ float red[256];
  int tid = threadIdx.x;
  int j = blockIdx.x;
  if (j >= 1024) {
    size_t i = (size_t)(j - 1024) * 256 + tid;  // 32768 half8s
    float4 a = ((const float4*)Whh)[i * 2];
    float4 b = ((const float4*)Whh)[i * 2 + 1];
    half8 h;
    h[0] = (_Float16)a.x; h[1] = (_Float16)a.y; h[2] = (_Float16)a.z; h[3] = (_Float16)a.w;
    h[4] = (_Float16)b.x; h[5] = (_Float16)b.y; h[6] = (_Float16)b.z; h[7] = (_Float16)b.w;
    ((half8*)whh16)[i] = h;
    return;
  }
  if (tid < Cz * HGz) wgs[tid] = Wg[tid];
  if (tid < HGz) bgs[tid] = bg[tid];
  __syncthreads();
  const float* row = Wih + (size_t)j * (Nz * HGz);
  float bacc = 0.f;
  for (int n = tid; n < Nz; n += 256) {
    const float* p = row + n * HGz;
    float w[16];
    float4 v0 = *(const float4*)p, v1 = *(const float4*)(p + 4);
    float4 v2 = *(const float4*)(p + 8), v3 = *(const float4*)(p + 12);
    w[0]=v0.x; w[1]=v0.y; w[2]=v0.z; w[3]=v0.w;
    w[4]=v1.x; w[5]=v1.y; w[6]=v1.z; w[7]=v1.w;
    w[8]=v2.x; w[9]=v2.y; w[10]=v2.z; w[11]=v2.w;
    w[12]=v3.x; w[13]=v3.y; w[14]=v3.z; w[15]=v3.w;
    half8 o;
#pragma unroll
    for (int c = 0; c < Cz; ++c) {
      float s = 0.f;
#pragma unroll
      for (int h = 0; h < HGz; ++h) s += w[h] * wgs[c * HGz + h];
      o[c] = (_Float16)s;
    }
#pragma unroll
    for (int h = 0; h < HGz; ++h) bacc += w[h] * bgs[h];
    *(half8*)(wc + (size_t)j * K2z + n * Cz) = o;
  }
  red[tid] = bacc;
  __syncthreads();
  for (int off = 128; off > 0; off >>= 1) {
    if (tid < off) red[tid] += red[tid + off];
    __syncthreads();
  }
  if (tid == 0) bgc[j] = red[0];
}

// xt: blocks 0..249 = batch-0 rows (ideg*x + CSR neighbor agg); blocks 250..7999 = fp16 cast of x batches 1..31.
__global__ void k_xt(const float* __restrict__ x, const float* __restrict__ ideg,
                     const int* __restrict__ roff, const int* __restrict__ cnt,
                     const int* __restrict__ csrs, const float* __restrict__ csrw,
                     _Float16* __restrict__ xt) {
  if (blockIdx.x >= 250) {
    size_t i = (size_t)(blockIdx.x - 250) * 256 + threadIdx.x;
    const float* src = x + (size_t)Tz * K2z;
    _Float16* dst = xt + (size_t)Tz * K2z;
    float4 a = ((const float4*)src)[i * 2];
    float4 b = ((const float4*)src)[i * 2 + 1];
    half8 h;
    h[0] = (_Float16)a.x; h[1] = (_Float16)a.y; h[2] = (_Float16)a.z; h[3] = (_Float16)a.w;
    h[4] = (_Float16)b.x; h[5] = (_Float16)b.y; h[6] = (_Float16)b.z; h[7] = (_Float16)b.w;
    ((half8*)dst)[i] = h;
    return;
  }
  int g = blockIdx.x * 256 + threadIdx.x;  // t*1000+n
  if (g >= Tz * Nz) return;
  int t = g / Nz, n = g % Nz;
  const float* xp = x + (size_t)g * Cz;
  float4 a = *(const float4*)xp, b = *(const float4*)(xp + 4);
  float id = ideg[n];
  float s[8] = {id*a.x, id*a.y, id*a.z, id*a.w, id*b.x, id*b.y, id*b.z, id*b.w};
  int i0 = roff[n], nc = cnt[n];
  for (int i = i0; i < i0 + nc; ++i) {
    int src = csrs[i];
    float wv = csrw[i];
    const float* q = x + ((size_t)t * Nz + src) * Cz;
    float4 u = *(const float4*)q, v = *(const float4*)(q + 4);
    s[0] += wv * u.x; s[1] += wv * u.y; s[2] += wv * u.z; s[3] += wv * u.w;
    s[4] += wv * v.x; s[5] += wv * v.y; s[6] += wv * v.z; s[7] += wv * v.w;
  }
  half8 h;
#pragma unroll
  for (int c = 0; c < 8; ++c) h[c] = (_Float16)s[c];
  *(half8*)(xt + (size_t)t * K2z + n * Cz) = h;
}

// ---------------- GEMM: preS[z][2048][1024] (fp16) = xt @ Wc^T, uneven split-K=8 ----------------
// z<7: K window 1024 (32 iters); z=7: 832 (26 iters). 1024 WGs -> 3-4 blocks/CU co-resident.
__global__ void __launch_bounds__(256) k_gemm(const _Float16* __restrict__ A,
                                              const _Float16* __restrict__ Bm,
                                              _Float16* __restrict__ Cp) {
  __shared__ _Float16 As[128 * 32];
  __shared__ _Float16 Bs[128 * 32];
  const int tid = threadIdx.x;
  const int lane = tid & 63;
  const int wave = tid >> 6;
  const int wm = wave & 1, wn = wave >> 1;
  const int quad = lane >> 4, l15 = lane & 15;
  const size_t tm = (size_t)blockIdx.x * 128;
  const size_t tn = (size_t)blockIdx.y * 128;
  const int k0 = blockIdx.z * 1024;
  const int iters = (blockIdx.z < 7) ? 32 : 26;   // 7*1024 + 832 = 8000
  _Float16* Cz_ = Cp + (size_t)blockIdx.z * Mz * G4z;
  const int srow = tid >> 2;
  const int skk = (tid & 3) * 8;
  const _Float16* gA0 = A + (tm + srow) * (size_t)K2z + k0 + skk;
  const _Float16* gA1 = gA0 + 64 * (size_t)K2z;
  const _Float16* gB0 = Bm + (tn + srow) * (size_t)K2z + k0 + skk;
  const _Float16* gB1 = gB0 + 64 * (size_t)K2z;
  _Float16* lA0 = &As[tid * 8];
  _Float16* lA1 = &As[2048 + tid * 8];
  _Float16* lB0 = &Bs[tid * 8];
  _Float16* lB1 = &Bs[2048 + tid * 8];
  floatx4 acc[4][4] = {};
  for (int kt = 0; kt < iters; ++kt) {
    __syncthreads();
    gl_lds16(gA0, lA0);
    gl_lds16(gA1, lA1);
    gl_lds16(gB0, lB0);
    gl_lds16(gB1, lB1);
    gA0 += 32; gA1 += 32; gB0 += 32; gB1 += 32;
    __syncthreads();
    half8 af[4], bf[4];
#pragma unroll
    for (int i = 0; i < 4; ++i)
      af[i] = *(const half8*)&As[(wm * 64 + i * 16 + l15) * 32 + quad * 8];
#pragma unroll
    for (int i = 0; i < 4; ++i)
      bf[i] = *(const half8*)&Bs[(wn * 64 + i * 16 + l15) * 32 + quad * 8];
#pragma unroll
    for (int mi = 0; mi < 4; ++mi)
#pragma unroll
      for (int ni = 0; ni < 4; ++ni)
        acc[mi][ni] = __builtin_amdgcn_mfma_f32_16x16x32_f16(af[mi], bf[ni], acc[mi][ni], 0, 0, 0);
  }
#pragma unroll
  for (int mi = 0; mi < 4; ++mi)
#pragma unroll
    for (int ni = 0; ni < 4; ++ni) {
      size_t r0 = tm + wm * 64 + mi * 16 + quad * 4;
      size_t cc = tn + wn * 64 + ni * 16 + l15;
#pragma unroll
      for (int q = 0; q < 4; ++q) Cz_[(r0 + q) * G4z + cc] = (_Float16)acc[mi][ni][q];
    }
}

// ---------------- reduce fp16 split-K + biases -> transposed fp16 pre[t][j][batch] ----------------
__global__ void k_reduce(const _Float16* __restrict__ preS, const float* __restrict__ bih,
                         const float* __restrict__ bhh, const float* __restrict__ bgc,
                         _Float16* __restrict__ preT) {
  int t = blockIdx.x;                      // 0..63
  int j = blockIdx.y * 256 + threadIdx.x;  // 0..1023
  float bias = bih[j] + bhh[j] + bgc[j];
  float v[32];
#pragma unroll
  for (int b = 0; b < 32; ++b) v[b] = bias;
  for (int s = 0; s < NSz; ++s) {
    const _Float16* base = preS + (size_t)s * Mz * G4z;
#pragma unroll
    for (int b = 0; b < 32; ++b)
      v[b] += (float)base[((size_t)b * Tz + t) * G4z + j];
  }
  half8 h[4];
#pragma unroll
  for (int i = 0; i < 32; ++i) ((_Float16*)h)[i] = (_Float16)v[i];
  half8* op = (half8*)(preT + ((size_t)t * G4z + j) * Bz);
#pragma unroll
  for (int i = 0; i < 4; ++i) op[i] = h[i];
}

// ---------------- LSTM: W-stationary LDS; h-exchange = NaN-sentinel data polling (no flags) ----------------
__global__ void __launch_bounds__(256) k_lstm4(const _Float16* __restrict__ Whh16,
                                               const _Float16* __restrict__ preT,
                                               unsigned long long* __restrict__ hx, // [8][65][256]
                                               float* __restrict__ hlast) {         // [32][256]
  __shared__ _Float16 Ws[256 * 264];     // 135 KB, W slice resident
  __shared__ _Float16 hs[2][16 * 264];   // parity-double-buffered h staging
  const int tid = threadIdx.x;
  const int d   = blockIdx.x >> 2;    // domain 0..7 (4 batches each)
  const int ws_ = blockIdx.x & 3;     // W-slice 0..3 (64 hl each)
  const int wv = tid >> 6;
  const int lane = tid & 63;
  const int quad = lane >> 4, l15 = lane & 15;

  for (int i = tid; i < 2 * 16 * 264; i += 256) ((_Float16*)hs)[i] = (_Float16)0.f;
#pragma unroll
  for (int rr = 0; rr < 2; ++rr) {
    int rp = (tid >> 1) + rr * 128;
    int g = rp >> 6, hl64 = rp & 63;
    int grow = g * 256 + ws_ * 64 + hl64;
    const half8* src = (const half8*)(Whh16 + (size_t)grow * HLz + (tid & 1) * 128);
    half8* dst = (half8*)&Ws[rp * 264 + (tid & 1) * 128];
#pragma unroll
    for (int u = 0; u < 16; ++u) dst[u] = src[u];
  }
  float cst[4] = {0.f, 0.f, 0.f, 0.f};
  const int hlG = ws_ * 64 + wv * 16 + l15;
  __syncthreads();

  for (int t = 0; t < Tz; ++t) {
    half4 pq[4];
    if (quad == 0) {
#pragma unroll
      for (int g = 0; g < 4; ++g)
        pq[g] = *(const half4*)(preT + ((size_t)t * G4z + g * HLz + hlG) * Bz + d * 4);
    }
    if (t > 0) {
      const unsigned long long* hsrc = hx + ((size_t)d * 65 + t) * 256;
      unsigned long long u;
      while ((u = __hip_atomic_load(hsrc + tid, __ATOMIC_RELAXED,
                                    __HIP_MEMORY_SCOPE_AGENT)) == SENT)
        __builtin_amdgcn_s_sleep(1);
      half4 hv = __builtin_bit_cast(half4, u);
      _Float16* hb = &hs[t & 1][0];
#pragma unroll
      for (int q = 0; q < 4; ++q) hb[q * 264 + tid] = hv[q];
    }
    __syncthreads();
    floatx4 acc[4] = {};
    const _Float16* hrow = &hs[t & 1][0];
#pragma unroll
    for (int kt = 0; kt < 8; ++kt) {
      half8 a = *(const half8*)&hrow[l15 * 264 + kt * 32 + quad * 8];
#pragma unroll
      for (int g = 0; g < 4; ++g) {
        half8 b = *(const half8*)&Ws[(g * 64 + wv * 16 + l15) * 264 + kt * 32 + quad * 8];
        acc[g] = __builtin_amdgcn_mfma_f32_16x16x32_f16(a, b, acc[g], 0, 0, 0);
      }
    }
    if (quad == 0) {
      half4 o;
#pragma unroll
      for (int q = 0; q < 4; ++q) {
        float gi = acc[0][q] + (float)pq[0][q];
        float gf = acc[1][q] + (float)pq[1][q];
        float gg = acc[2][q] + (float)pq[2][q];
        float go = acc[3][q] + (float)pq[3][q];
        float iv = sigm(gi), fv = sigm(gf), gv = tanhh(gg), ov = sigm(go);
        float cn = fv * cst[q] + iv * gv;
        cst[q] = cn;
        float hn = ov * tanhh(cn);
        o[q] = (_Float16)hn;
        if (t == Tz - 1) hlast[(size_t)(d * 4 + q) * HLz + hlG] = hn;
      }
      if (t < Tz - 1) {
        __hip_atomic_store(hx + ((size_t)d * 65 + t + 1) * 256 + hlG,
                           __builtin_bit_cast(unsigned long long, o),
                           __ATOMIC_RELAXED, __HIP_MEMORY_SCOPE_AGENT);
      }
    }
  }
}

// out[b,o] = h_last[b,:] @ W_proj[o,:] + b_proj[o]
__global__ void k_proj(const float* __restrict__ hlast, const float* __restrict__ Wp,
                       const float* __restrict__ bp, float* __restrict__ out) {
  int idx = blockIdx.x * 256 + threadIdx.x;
  if (idx >= Bz * OUTz) return;
  int b = idx / OUTz, o = idx % OUTz;
  const float* h = hlast + (size_t)b * HLz;
  const float* wr = Wp + (size_t)o * HLz;
  float s = 0.f;
  for (int k = 0; k < HLz; k += 4) {
    float4 hv = *(const float4*)&h[k];
    float4 wv = *(const float4*)&wr[k];
    s += hv.x * wv.x + hv.y * wv.y + hv.z * wv.z + hv.w * wv.w;
  }
  out[idx] = s + bp[o];
}

extern "C" void kernel_launch(void* const* d_in, const int* in_sizes, int n_in,
                              void* d_out, int out_size, void* d_ws, size_t ws_size,
                              hipStream_t stream) {
  const float* x   = (const float*)d_in[0];
  const int*   ei  = (const int*)d_in[1];
  const float* ew  = (const float*)d_in[2];
  const float* Wg  = (const float*)d_in[3];
  const float* bg  = (const float*)d_in[4];
  const float* Wih = (const float*)d_in[5];
  const float* Whh = (const float*)d_in[6];
  const float* bih = (const float*)d_in[7];
  const float* bhh = (const float*)d_in[8];
  const float* Wp  = (const float*)d_in[9];
  const float* bp  = (const float*)d_in[10];
  float* out = (float*)d_out;
  char* ws = (char*)d_ws;
  if (ws_size < WS_NEED) return;

  float* ideg  = (float*)(ws + OFF_IDEG);
  int*   cnt   = (int*)(ws + OFF_CNT);
  int*   roff  = (int*)(ws + OFF_ROFF);
  int*   csrs  = (int*)(ws + OFF_CSRS);
  float* csrw  = (float*)(ws + OFF_CSRW);
  float* hlast = (float*)(ws + OFF_HLAST);
  _Float16* preT  = (_Float16*)(ws + OFF_PRE16T);
  _Float16* whh16 = (_Float16*)(ws + OFF_WHH16);
  unsigned long long* hx = (unsigned long long*)(ws + OFF_HX);
  float* bgc   = (float*)(ws + OFF_BGC);
  _Float16* xt    = (_Float16*)(ws + OFF_XT);
  _Float16* wc    = (_Float16*)(ws + OFF_WC);
  _Float16* preS  = (_Float16*)(ws + OFF_PRES);

  // hx = NaN sentinel (byte-uniform); slot t=0 is never read (h0=0 handled in-kernel)
  hipMemsetAsync(ws + OFF_HX, 0x7E, (size_t)8 * 65 * 256 * 8, stream);

  k_prep<<<1, 1024, 0, stream>>>(ei, ew, ideg, cnt, roff, csrs, csrw);
  k_fold<<<1152, 256, 0, stream>>>(Wih, Wg, bg, wc, bgc, Whh, whh16);
  k_xt<<<8000, 256, 0, stream>>>(x, ideg, roff, cnt, csrs, csrw, xt);
  k_gemm<<<dim3(16, 8, NSz), 256, 0, stream>>>(xt, wc, preS);
  k_reduce<<<dim3(Tz, 4), 256, 0, stream>>>(preS, bih, bhh, bgc, preT);
  k_lstm4<<<32, 256, 0, stream>>>(whh16, preT, hx, hlast);
  k_proj<<<3, 256, 0, stream>>>(hlast, Wp, bp, out);
}